// Round 6
// baseline (4076.842 us; speedup 1.0000x reference)
//
#include <hip/hip_runtime.h>
#include <hip/hip_bf16.h>

// HAN_81801947119983 — round 6: barrier-light bigru_wave (2 waves/block, reg-staged G
// double buffer, bf16 hi/lo state mirror only). GEMM/attn/head unchanged from R5.
// B=64, D=40, S=50, E=200, H=128, C=10. N1=2560 word rows (T=50), 64 doc rows (T=40).
// G cols: [0:256) fw gates, [256:384) fw cand, [384:640) bw gates, [640:768) bw cand.
// MFMA 16x16x32 bf16: A frag lane holds A[m=lane&15][k=quad*8+j]; B frag B[k][n=lane&15];
// C/D col=lane&15, row=quad*4+reg.  Pack uint4 idx: ((tile*KC+kc)*4+quad)*16+(lane&15).

typedef __attribute__((ext_vector_type(8))) short short8;
typedef __attribute__((ext_vector_type(4))) float f32x4;

__device__ __forceinline__ float fsigmoid(float x) { return 1.f / (1.f + __expf(-x)); }
__device__ __forceinline__ float ftanh(float x)    { float e = __expf(2.f * x); return 1.f - 2.f / (e + 1.f); }

__device__ __forceinline__ unsigned short f2bf(float x) {
    unsigned int u = __builtin_bit_cast(unsigned int, x);
    u += 0x7fffu + ((u >> 16) & 1u);
    return (unsigned short)(u >> 16);
}
__device__ __forceinline__ float bf2f(unsigned short h) {
    unsigned int u = ((unsigned int)h) << 16;
    return __builtin_bit_cast(float, u);
}
__device__ __forceinline__ uint4 pack8(const unsigned short* v) {
    uint4 r;
    r.x = (unsigned int)v[0] | ((unsigned int)v[1] << 16);
    r.y = (unsigned int)v[2] | ((unsigned int)v[3] << 16);
    r.z = (unsigned int)v[4] | ((unsigned int)v[5] << 16);
    r.w = (unsigned int)v[6] | ((unsigned int)v[7] << 16);
    return r;
}
__device__ __forceinline__ void cvt8(const float* v, short8& hi, short8& lo) {
    unsigned short h[8], l[8];
#pragma unroll
    for (int j = 0; j < 8; ++j) {
        unsigned short hh = f2bf(v[j]);
        h[j] = hh;
        l[j] = f2bf(v[j] - bf2f(hh));
    }
    uint4 uh = pack8(h), ul = pack8(l);
    hi = __builtin_bit_cast(short8, uh);
    lo = __builtin_bit_cast(short8, ul);
}

// ---------------- weight concat: W[E,768] = [wg_f | wc_f | wg_b | wc_b], bias[768] ----------------
__global__ __launch_bounds__(256) void pack_weights(
    const float* __restrict__ wg_f, const float* __restrict__ bg_f,
    const float* __restrict__ wc_f, const float* __restrict__ bc_f,
    const float* __restrict__ wg_b, const float* __restrict__ bg_b,
    const float* __restrict__ wc_b, const float* __restrict__ bc_b,
    float* __restrict__ W, float* __restrict__ bias, int E)
{
    int idx = blockIdx.x * 256 + threadIdx.x;
    if (idx < 768) {
        int c = idx; float v;
        if (c < 256) v = bg_f[c];
        else if (c < 384) v = bc_f[c - 256];
        else if (c < 640) v = bg_b[c - 384];
        else v = bc_b[c - 640];
        bias[c] = v;
    }
    if (idx >= E * 768) return;
    int k = idx / 768, c = idx - k * 768;
    float v;
    if (c < 256) v = wg_f[k * 256 + c];
    else if (c < 384) v = wc_f[k * 128 + (c - 256)];
    else if (c < 640) v = wg_b[k * 256 + (c - 384)];
    else v = wc_b[k * 128 + (c - 640)];
    W[idx] = v;
}

// ---------------- pack A (row-major [Mr x Ks] fp32) into frag-order hi/lo bf16 ----------------
__global__ __launch_bounds__(256) void pack_a_frag(
    const float* __restrict__ src, uint4* __restrict__ dstH, uint4* __restrict__ dstL,
    int Mr16, int KC, int Ks)
{
    int idx = blockIdx.x * 256 + threadIdx.x;
    if (idx >= Mr16 * KC * 64) return;
    int lane = idx & 63;
    int g = idx >> 6;
    int mb = g / KC, kc = g - mb * KC;
    int m = lane & 15, quad = lane >> 4;
    int row = mb * 16 + m;
    int k0 = kc * 32 + quad * 8;
    const float* s = src + (size_t)row * Ks;
    unsigned short hi[8], lo[8];
#pragma unroll
    for (int j = 0; j < 8; ++j) {
        float x = (k0 + j < Ks) ? s[k0 + j] : 0.f;
        unsigned short h = f2bf(x);
        hi[j] = h;
        lo[j] = f2bf(x - bf2f(h));
    }
    dstH[idx] = pack8(hi);
    dstL[idx] = pack8(lo);
}

// ---------------- pack W (row-major [Ks x N] fp32) into frag-order hi/lo bf16 ----------------
__global__ __launch_bounds__(256) void pack_w_frag(
    const float* __restrict__ src, uint4* __restrict__ dstH, uint4* __restrict__ dstL,
    int N16, int KC, int Ks, int N)
{
    int idx = blockIdx.x * 256 + threadIdx.x;
    if (idx >= N16 * KC * 64) return;
    int lane = idx & 63;
    int g = idx >> 6;
    int nb = g / KC, kc = g - nb * KC;
    int m = lane & 15, quad = lane >> 4;
    int n = nb * 16 + m;
    int k0 = kc * 32 + quad * 8;
    unsigned short hi[8], lo[8];
#pragma unroll
    for (int j = 0; j < 8; ++j) {
        float x = (k0 + j < Ks) ? src[(size_t)(k0 + j) * N + n] : 0.f;
        unsigned short h = f2bf(x);
        hi[j] = h;
        lo[j] = f2bf(x - bf2f(h));
    }
    dstH[idx] = pack8(hi);
    dstL[idx] = pack8(lo);
}

// ---------------- merged recurrent weight pack: 4 matrices per level ----------------
__global__ __launch_bounds__(256) void pack_rec(
    const float* __restrict__ wgf, const float* __restrict__ wgb,
    const float* __restrict__ wcf, const float* __restrict__ wcb,
    uint4* __restrict__ RgH, uint4* __restrict__ RgL,
    uint4* __restrict__ RcH, uint4* __restrict__ RcL)
{
    int sel = blockIdx.y;
    const float* src; uint4 *dH, *dL; int N16, N;
    if (sel == 0)      { src = wgf; dH = RgH;        dL = RgL;        N16 = 16; N = 256; }
    else if (sel == 1) { src = wgb; dH = RgH + 4096; dL = RgL + 4096; N16 = 16; N = 256; }
    else if (sel == 2) { src = wcf; dH = RcH;        dL = RcL;        N16 = 8;  N = 128; }
    else               { src = wcb; dH = RcH + 2048; dL = RcL + 2048; N16 = 8;  N = 128; }
    int idx = blockIdx.x * 256 + threadIdx.x;
    if (idx >= N16 * 4 * 64) return;
    int lane = idx & 63;
    int g = idx >> 6;
    int nb = g / 4, kc = g - nb * 4;
    int m = lane & 15, quad = lane >> 4;
    int n = nb * 16 + m;
    int k0 = kc * 32 + quad * 8;
    unsigned short hi[8], lo[8];
#pragma unroll
    for (int j = 0; j < 8; ++j) {
        float x = src[(size_t)(k0 + j) * N + n];
        unsigned short h = f2bf(x);
        hi[j] = h;
        lo[j] = f2bf(x - bf2f(h));
    }
    dH[idx] = pack8(hi);
    dL[idx] = pack8(lo);
}

// ---------------- MFMA GEMM: C = A @ W + bias, split-bf16 3-product ----------------
__global__ __launch_bounds__(256) void mfma_gemm(
    const uint4* __restrict__ Ah, const uint4* __restrict__ Al,
    const uint4* __restrict__ Bh, const uint4* __restrict__ Bl,
    const float* __restrict__ bias, float* __restrict__ C,
    int KC, int ldc, int act)
{
    int tid = threadIdx.x;
    int lane = tid & 63;
    int w = tid >> 6;
    int wm = w >> 1, wn = w & 1;
    int quad = lane >> 4, m = lane & 15;
    int bm = blockIdx.x, bn = blockIdx.y;
    f32x4 acc[4][4];
#pragma unroll
    for (int i = 0; i < 4; ++i)
#pragma unroll
        for (int j = 0; j < 4; ++j) acc[i][j] = (f32x4){0.f, 0.f, 0.f, 0.f};

    size_t aBase[4], bBase[4];
#pragma unroll
    for (int i = 0; i < 4; ++i) {
        aBase[i] = ((size_t)(bm * 8 + wm * 4 + i) * KC) * 64 + quad * 16 + m;
        bBase[i] = ((size_t)(bn * 8 + wn * 4 + i) * KC) * 64 + quad * 16 + m;
    }
    for (int kc = 0; kc < KC; ++kc) {
        short8 ah[4], al[4], bh[4], bl[4];
#pragma unroll
        for (int i = 0; i < 4; ++i) {
            ah[i] = __builtin_bit_cast(short8, Ah[aBase[i]]);
            al[i] = __builtin_bit_cast(short8, Al[aBase[i]]);
            bh[i] = __builtin_bit_cast(short8, Bh[bBase[i]]);
            bl[i] = __builtin_bit_cast(short8, Bl[bBase[i]]);
            aBase[i] += 64; bBase[i] += 64;
        }
#pragma unroll
        for (int i = 0; i < 4; ++i)
#pragma unroll
            for (int j = 0; j < 4; ++j) {
                acc[i][j] = __builtin_amdgcn_mfma_f32_16x16x32_bf16(ah[i], bh[j], acc[i][j], 0, 0, 0);
                acc[i][j] = __builtin_amdgcn_mfma_f32_16x16x32_bf16(ah[i], bl[j], acc[i][j], 0, 0, 0);
                acc[i][j] = __builtin_amdgcn_mfma_f32_16x16x32_bf16(al[i], bh[j], acc[i][j], 0, 0, 0);
            }
    }
#pragma unroll
    for (int i = 0; i < 4; ++i) {
        int row0 = bm * 128 + wm * 64 + i * 16 + quad * 4;
#pragma unroll
        for (int j = 0; j < 4; ++j) {
            int col = bn * 128 + wn * 64 + j * 16 + m;
            float b = bias[col];
#pragma unroll
            for (int r = 0; r < 4; ++r) {
                float v = acc[i][j][r] + b;
                if (act) v = ftanh(v);
                C[(size_t)(row0 + r) * ldc + col] = v;
            }
        }
    }
}

// ---------------- BiGRU recurrence v4: 16 rows x 1 dir per block, 2 waves ----------------
// Wave w owns output-column halves (gate nt w*8.., cand nt w*4..). G double-buffered in
// LDS via 13 float4 regs/lane loaded for t+1 at step top, ds_written at step end (vmcnt
// cover = full step, no conservative drains). State h exists ONLY as bf16 hi/lo A-frag
// mirror (hi+lo == value the MFMA sees; fp32 reconstruction err ~2^-17).
__global__ __launch_bounds__(128) void bigru_wave(
    const float* __restrict__ G,      // [nRows*T, 768] chunk-local
    const uint4* __restrict__ WgH, const uint4* __restrict__ WgL,  // [2 dirs][16 nt][4 kc][64]
    const uint4* __restrict__ WcH, const uint4* __restrict__ WcL,  // [2 dirs][8 nt][4 kc][64]
    const int* __restrict__ lens,
    float* __restrict__ outbuf,       // [nRows*T, 256] chunk-local (zeros at invalid)
    int rowOff, int T)
{
    __shared__ float Gb[2][6400];             // 16 rows x 388 (pad) + chunk pad; 51.2 KB
    __shared__ uint4 hfH[4][64], hfL[4][64];  // h A-frag mirror (k=0..127)
    __shared__ uint4 rfH[4][64], rfL[4][64];  // r*h A-frag
    __shared__ float zs[16][130];

    const int tid = threadIdx.x;
    const int lane = tid & 63, w = tid >> 6;
    const int quad = lane >> 4, mc = lane & 15;
    const int dir = blockIdx.x & 1;
    const int rg0 = (blockIdx.x >> 1) * 16;

    unsigned short* hfHu = (unsigned short*)hfH;
    unsigned short* hfLu = (unsigned short*)hfL;
    unsigned short* rfHu = (unsigned short*)rfH;
    unsigned short* rfLu = (unsigned short*)rfL;

    for (int i = tid; i < 256; i += 128) {
        hfH[0][i] = (uint4){0, 0, 0, 0};
        hfL[0][i] = (uint4){0, 0, 0, 0};
    }
    int Lr[4];
#pragma unroll
    for (int r = 0; r < 4; ++r) Lr[r] = lens[rowOff + rg0 + quad * 4 + r];

    // staging meta: wave0 chunks 0..12, wave1 chunks 13..24 (granule g = k*64+lane)
    const int k0 = w * 13;
    const int nk = w ? 12 : 13;
    int meta[13];
    float4 sreg[13];
    const char* Gblk = (const char*)(G + ((size_t)rg0 * T * 768 + dir * 384));
#pragma unroll
    for (int k = 0; k < 13; ++k) {
        if (k < nk) {
            int g = (k0 + k) * 64 + lane;
            int m = g / 97; if (m > 15) m = 15;
            int c4 = g - m * 97; if (c4 > 96) c4 = 96;
            int L = lens[rowOff + rg0 + m];
            meta[k] = (m * T * 3072 + c4 * 16) | (L << 26);
        }
    }
    // preload + write t=0
#pragma unroll
    for (int k = 0; k < 13; ++k) if (k < nk) {
        int off = meta[k] & 0x03FFFFFF;
        int L = (int)(((unsigned int)meta[k]) >> 26);
        int sel = (dir && 0 < L) ? (L - 1) : 0;
        sreg[k] = *(const float4*)(Gblk + (size_t)off + (size_t)sel * 3072);
    }
    {
        float4* dst = (float4*)&Gb[0][0];
#pragma unroll
        for (int k = 0; k < 13; ++k) if (k < nk) dst[(k0 + k) * 64 + lane] = sreg[k];
    }
    __syncthreads();

    for (int t = 0; t < T; ++t) {
        const int buf = t & 1;
        const float* Gv = &Gb[buf][0];
        // a) issue loads for t+1 (consumed at step end -> full-step latency cover)
        if (t + 1 < T) {
#pragma unroll
            for (int k = 0; k < 13; ++k) if (k < nk) {
                int off = meta[k] & 0x03FFFFFF;
                int L = (int)(((unsigned int)meta[k]) >> 26);
                int t1 = t + 1;
                int sel = (dir && t1 < L) ? (L - 1 - t1) : t1;
                sreg[k] = *(const float4*)(Gblk + (size_t)off + (size_t)sel * 3072);
            }
        }
        // b) gate MFMA: wave's nt = w*8 .. w*8+7
        f32x4 ga[8];
#pragma unroll
        for (int i = 0; i < 8; ++i) ga[i] = (f32x4){0.f, 0.f, 0.f, 0.f};
#pragma unroll
        for (int kc = 0; kc < 4; ++kc) {
            short8 ah = __builtin_bit_cast(short8, hfH[kc][lane]);
            short8 al = __builtin_bit_cast(short8, hfL[kc][lane]);
#pragma unroll
            for (int i = 0; i < 8; ++i) {
                size_t idx = (((size_t)(dir * 16 + w * 8 + i) * 4 + kc) << 6) + lane;
                short8 bh = __builtin_bit_cast(short8, WgH[idx]);
                short8 bl = __builtin_bit_cast(short8, WgL[idx]);
                ga[i] = __builtin_amdgcn_mfma_f32_16x16x32_bf16(ah, bh, ga[i], 0, 0, 0);
                ga[i] = __builtin_amdgcn_mfma_f32_16x16x32_bf16(ah, bl, ga[i], 0, 0, 0);
                ga[i] = __builtin_amdgcn_mfma_f32_16x16x32_bf16(al, bh, ga[i], 0, 0, 0);
            }
        }
        // c) gate elementwise: wave0 -> rh frags, wave1 -> z
        if (w == 0) {
#pragma unroll
            for (int i = 0; i < 8; ++i) {
#pragma unroll
                for (int r = 0; r < 4; ++r) {
                    int m = quad * 4 + r;
                    int n = i * 16 + mc;                       // r-gate col = h k-dim
                    float s = fsigmoid(ga[i][r] + Gv[m * 388 + n]);
                    int fi = (((n >> 5) * 64 + ((n >> 3) & 3) * 16 + m) << 3) + (n & 7);
                    float h = bf2f(hfHu[fi]) + bf2f(hfLu[fi]);
                    float rh = s * h;
                    unsigned short hi = f2bf(rh);
                    rfHu[fi] = hi;
                    rfLu[fi] = f2bf(rh - bf2f(hi));
                }
            }
        } else {
#pragma unroll
            for (int i = 0; i < 8; ++i) {
#pragma unroll
                for (int r = 0; r < 4; ++r) {
                    int m = quad * 4 + r;
                    int n = i * 16 + mc;                       // z col (global gate col 128+n)
                    float s = fsigmoid(ga[i][r] + Gv[m * 388 + 128 + n]);
                    zs[m][n] = s;
                }
            }
        }
        __syncthreads();
        // e) cand MFMA: wave's cand nt = w*4 .. w*4+3
        f32x4 ca[4];
#pragma unroll
        for (int i = 0; i < 4; ++i) ca[i] = (f32x4){0.f, 0.f, 0.f, 0.f};
#pragma unroll
        for (int kc = 0; kc < 4; ++kc) {
            short8 ar = __builtin_bit_cast(short8, rfH[kc][lane]);
            short8 al = __builtin_bit_cast(short8, rfL[kc][lane]);
#pragma unroll
            for (int i = 0; i < 4; ++i) {
                size_t idx = (((size_t)(dir * 8 + w * 4 + i) * 4 + kc) << 6) + lane;
                short8 bh = __builtin_bit_cast(short8, WcH[idx]);
                short8 bl = __builtin_bit_cast(short8, WcL[idx]);
                ca[i] = __builtin_amdgcn_mfma_f32_16x16x32_bf16(ar, bh, ca[i], 0, 0, 0);
                ca[i] = __builtin_amdgcn_mfma_f32_16x16x32_bf16(ar, bl, ca[i], 0, 0, 0);
                ca[i] = __builtin_amdgcn_mfma_f32_16x16x32_bf16(al, bh, ca[i], 0, 0, 0);
            }
        }
        // f) update: wave covers cols w*64 .. w*64+63
#pragma unroll
        for (int i = 0; i < 4; ++i) {
#pragma unroll
            for (int r = 0; r < 4; ++r) {
                int m = quad * 4 + r;
                int cn = (w * 4 + i) * 16 + mc;
                float cd = ftanh(ca[i][r] + Gv[m * 388 + 256 + cn]);
                float z = zs[m][cn];
                int fi = (((cn >> 5) * 64 + ((cn >> 3) & 3) * 16 + m) << 3) + (cn & 7);
                float h = bf2f(hfHu[fi]) + bf2f(hfLu[fi]);
                float hn = z * h + (1.f - z) * cd;
                bool valid = (t < Lr[r]);
                int tir = (dir && valid) ? (Lr[r] - 1 - t) : t;
                if (valid) {
                    unsigned short hi = f2bf(hn);
                    hfHu[fi] = hi;
                    hfLu[fi] = f2bf(hn - bf2f(hi));
                }
                outbuf[((size_t)(rg0 + m) * T + tir) * 256 + dir * 128 + cn] = valid ? hn : 0.f;
            }
        }
        // g) publish staged t+1 (waits on (a)'s loads — issued a full step ago)
        if (t + 1 < T) {
            float4* dst = (float4*)&Gb[buf ^ 1][0];
#pragma unroll
            for (int k = 0; k < 13; ++k) if (k < nk) dst[(k0 + k) * 64 + lane] = sreg[k];
        }
        __syncthreads();
    }
}

// ---------------- fused attention: proj MFMA + score + softmax + weighted sum ----------------
__global__ __launch_bounds__(256) void attn_fused(
    const float* __restrict__ outv,   // [n*T, 256]
    const uint4* __restrict__ WaH, const uint4* __restrict__ WaL,  // [8 nt][8 kc][64]
    const float* __restrict__ ba, const float* __restrict__ u,
    float* __restrict__ att_out,      // rows (attRowOff+n)*T
    float* __restrict__ vec,          // [n, 256]
    int T, int attRowOff)
{
    __shared__ float lowS[50][260];
    __shared__ float scoreS[64];
    __shared__ float attS[64];
    int n = blockIdx.x;
    int tid = threadIdx.x;
    int lane = tid & 63, w = tid >> 6;
    int quad = lane >> 4, mc = lane & 15;

    const float4* src4 = (const float4*)(outv + (size_t)n * T * 256);
    for (int idx = tid; idx < T * 64; idx += 256) {
        int row = idx >> 6, c4 = idx & 63;
        float4 v = src4[idx];
        *(float4*)&lowS[row][c4 * 4] = v;
    }
    __syncthreads();

    f32x4 acc[8];
#pragma unroll
    for (int j = 0; j < 8; ++j) acc[j] = (f32x4){0.f, 0.f, 0.f, 0.f};
    int rowA = w * 16 + mc;
    bool rowValid = rowA < T;
#pragma unroll
    for (int kc = 0; kc < 8; ++kc) {
        float v[8];
        if (rowValid) {
            const float* p = &lowS[rowA][kc * 32 + quad * 8];
#pragma unroll
            for (int j = 0; j < 8; ++j) v[j] = p[j];
        } else {
#pragma unroll
            for (int j = 0; j < 8; ++j) v[j] = 0.f;
        }
        short8 ah, al;
        cvt8(v, ah, al);
#pragma unroll
        for (int nt = 0; nt < 8; ++nt) {
            size_t idx = (((size_t)nt * 8 + kc) << 6) + lane;
            short8 bh = __builtin_bit_cast(short8, WaH[idx]);
            short8 bl = __builtin_bit_cast(short8, WaL[idx]);
            acc[nt] = __builtin_amdgcn_mfma_f32_16x16x32_bf16(ah, bh, acc[nt], 0, 0, 0);
            acc[nt] = __builtin_amdgcn_mfma_f32_16x16x32_bf16(ah, bl, acc[nt], 0, 0, 0);
            acc[nt] = __builtin_amdgcn_mfma_f32_16x16x32_bf16(al, bh, acc[nt], 0, 0, 0);
        }
    }
    float sc[4] = {0.f, 0.f, 0.f, 0.f};
#pragma unroll
    for (int nt = 0; nt < 8; ++nt) {
        int col = nt * 16 + mc;
        float bb = ba[col], uu = u[col];
#pragma unroll
        for (int r = 0; r < 4; ++r)
            sc[r] += ftanh(acc[nt][r] + bb) * uu;
    }
#pragma unroll
    for (int off = 1; off < 16; off <<= 1) {
#pragma unroll
        for (int r = 0; r < 4; ++r) sc[r] += __shfl_xor(sc[r], off);
    }
    if (mc == 0) {
#pragma unroll
        for (int r = 0; r < 4; ++r) scoreS[w * 16 + quad * 4 + r] = sc[r];
    }
    __syncthreads();
    if (w == 0) {
        float s = (lane < T) ? scoreS[lane] : -3.402823466e38f;
        float m = s;
#pragma unroll
        for (int off = 1; off < 64; off <<= 1) m = fmaxf(m, __shfl_xor(m, off));
        float e = (lane < T) ? __expf(s - m) : 0.f;
        float sum = e;
#pragma unroll
        for (int off = 1; off < 64; off <<= 1) sum += __shfl_xor(sum, off);
        float att = e / sum;
        attS[lane] = att;
        if (lane < T) att_out[(size_t)(attRowOff + n) * T + lane] = att;
    }
    __syncthreads();
    float a = 0.f;
    for (int t = 0; t < T; ++t) a += attS[t] * lowS[t][tid];
    vec[(size_t)n * 256 + tid] = a;
}

// ---------------- head: logits, log-softmax, loss(+reg), predict, accuracy ----------------
__global__ __launch_bounds__(256) void head_kernel(
    const float* __restrict__ dvec, const float* __restrict__ wp, const float* __restrict__ bp,
    const int* __restrict__ y,
    const float* __restrict__ wa_l, const float* __restrict__ ba_l, const float* __restrict__ wa_h,
    const float* __restrict__ uw, const float* __restrict__ us,
    float* __restrict__ out)
{
    __shared__ float lg[64][10];
    __shared__ float red[256];
    int tid = threadIdx.x;
    for (int idx = tid; idx < 640; idx += 256) {
        int r = idx / 10, c = idx % 10;
        float a = bp[c];
        const float* dv = dvec + r * 256;
        for (int k = 0; k < 256; ++k) a += dv[k] * wp[k * 10 + c];
        lg[r][c] = a;
    }
    __syncthreads();
    float lossv = 0.f, corr = 0.f;
    if (tid < 64) {
        float m = lg[tid][0]; int arg = 0;
        for (int c = 1; c < 10; ++c) if (lg[tid][c] > m) { m = lg[tid][c]; arg = c; }
        float se = 0.f;
        for (int c = 0; c < 10; ++c) se += __expf(lg[tid][c] - m);
        float lse = m + __logf(se);
        int yy = y[tid];
        lossv = -(lg[tid][yy] - lse);
        corr = (yy == arg) ? 1.f : 0.f;
        out[1 + tid] = (float)arg;
    }
    float rs = 0.f;
    for (int i = tid; i < 32768; i += 256) {
        float v = wa_l[i]; rs += v * v;
        float w = wa_h[i]; rs += 2.f * w * w;
    }
    if (tid < 128) {
        float v1 = ba_l[tid], v2 = uw[tid], v3 = us[tid];
        rs += v1 * v1 + v2 * v2 + v3 * v3;
    }
    red[tid] = lossv; __syncthreads();
    for (int o = 128; o > 0; o >>= 1) { if (tid < o) red[tid] += red[tid + o]; __syncthreads(); }
    float totLoss = red[0]; __syncthreads();
    red[tid] = corr; __syncthreads();
    for (int o = 128; o > 0; o >>= 1) { if (tid < o) red[tid] += red[tid + o]; __syncthreads(); }
    float totCorr = red[0]; __syncthreads();
    red[tid] = rs; __syncthreads();
    for (int o = 128; o > 0; o >>= 1) { if (tid < o) red[tid] += red[tid + o]; __syncthreads(); }
    float totReg = red[0];
    if (tid == 0) {
        out[0] = totLoss / 64.f + 0.01f * totReg;
        out[65] = totCorr / 64.f;
    }
}

extern "C" void kernel_launch(void* const* d_in, const int* in_sizes, int n_in,
                              void* d_out, int out_size, void* d_ws, size_t ws_size,
                              hipStream_t stream)
{
    const float* X    = (const float*)d_in[0];
    const int*   y    = (const int*)d_in[1];
    const int*   slen = (const int*)d_in[2];
    const int*   dlen = (const int*)d_in[3];
    const float* wgf_l = (const float*)d_in[6];
    const float* bgf_l = (const float*)d_in[7];
    const float* wcf_l = (const float*)d_in[8];
    const float* bcf_l = (const float*)d_in[9];
    const float* wgb_l = (const float*)d_in[10];
    const float* bgb_l = (const float*)d_in[11];
    const float* wcb_l = (const float*)d_in[12];
    const float* bcb_l = (const float*)d_in[13];
    const float* wa_l  = (const float*)d_in[14];
    const float* ba_l  = (const float*)d_in[15];
    const float* wgf_h = (const float*)d_in[16];
    const float* bgf_h = (const float*)d_in[17];
    const float* wcf_h = (const float*)d_in[18];
    const float* bcf_h = (const float*)d_in[19];
    const float* wgb_h = (const float*)d_in[20];
    const float* bgb_h = (const float*)d_in[21];
    const float* wcb_h = (const float*)d_in[22];
    const float* bcb_h = (const float*)d_in[23];
    const float* wa_h  = (const float*)d_in[24];
    const float* ba_h  = (const float*)d_in[25];
    const float* uw    = (const float*)d_in[26];
    const float* us    = (const float*)d_in[27];
    const float* wp    = (const float*)d_in[28];
    const float* bp    = (const float*)d_in[29];
    float* out = (float*)d_out;

    int NCH = 1;
    while (NCH < 8) {
        size_t M1t = 128000ull / NCH;
        size_t needB = (M1t * 1248ull + 5200000ull) * 4ull;
        if (needB <= ws_size) break;
        NCH *= 2;
    }
    size_t nRows = 2560 / NCH;
    size_t M1 = nRows * 50;

    float* G1     = (float*)d_ws;            // M1*768
    float* low    = G1 + M1 * 768;           // M1*256
    float* AXf    = low + M1 * 256;          // M1*224
    float* sent   = AXf + M1 * 224;          // 655360
    float* Gs     = sent + 655360;           // 1966080
    float* high   = Gs + 1966080;            // 655360
    float* dvec   = high + 655360;           // 16384
    float* pSf    = dvec + 16384;            // 655360
    float* WpackL = pSf + 655360;            // 153600
    float* biasL  = WpackL + 153600;         // 768
    float* WLf    = biasL + 768;             // 172032
    float* WpackH = WLf + 172032;            // 196608
    float* biasH  = WpackH + 196608;         // 768
    float* WHf    = biasH + 768;             // 196608
    float* WaLf   = WHf + 196608;            // 32768
    float* WaHf   = WaLf + 32768;            // 32768
    float* RgLf   = WaHf + 32768;            // 65536
    float* RcLf   = RgLf + 65536;            // 32768
    float* RgHf   = RcLf + 32768;            // 65536
    float* RcHf   = RgHf + 65536;            // 32768

    uint4* AXh = (uint4*)AXf;           uint4* AXl = (uint4*)(AXf + M1 * 112);
    uint4* pSh = (uint4*)pSf;           uint4* pSl = (uint4*)(pSf + 327680);
    uint4* WLh = (uint4*)WLf;           uint4* WLl = (uint4*)(WLf + 86016);
    uint4* WHh = (uint4*)WHf;           uint4* WHl = (uint4*)(WHf + 98304);
    uint4* WaLh = (uint4*)WaLf;         uint4* WaLl = (uint4*)(WaLf + 16384);
    uint4* WaHh = (uint4*)WaHf;         uint4* WaHl = (uint4*)(WaHf + 16384);
    uint4* RgLH = (uint4*)RgLf;         uint4* RgLL = (uint4*)(RgLf + 32768);
    uint4* RcLH = (uint4*)RcLf;         uint4* RcLL = (uint4*)(RcLf + 16384);
    uint4* RgHH = (uint4*)RgHf;         uint4* RgHL = (uint4*)(RgHf + 32768);
    uint4* RcHH = (uint4*)RcHf;         uint4* RcHL = (uint4*)(RcHf + 16384);

    pack_weights<<<600, 256, 0, stream>>>(wgf_l, bgf_l, wcf_l, bcf_l, wgb_l, bgb_l, wcb_l, bcb_l,
                                          WpackL, biasL, 200);
    pack_weights<<<768, 256, 0, stream>>>(wgf_h, bgf_h, wcf_h, bcf_h, wgb_h, bgb_h, wcb_h, bcb_h,
                                          WpackH, biasH, 256);
    pack_w_frag<<<84, 256, 0, stream>>>(WpackL, WLh, WLl, 48, 7, 200, 768);
    pack_w_frag<<<96, 256, 0, stream>>>(WpackH, WHh, WHl, 48, 8, 256, 768);
    pack_w_frag<<<16, 256, 0, stream>>>(wa_l, WaLh, WaLl, 8, 8, 256, 128);
    pack_w_frag<<<16, 256, 0, stream>>>(wa_h, WaHh, WaHl, 8, 8, 256, 128);
    pack_rec<<<dim3(16, 4), 256, 0, stream>>>(wgf_l + 200 * 256, wgb_l + 200 * 256,
                                              wcf_l + 200 * 128, wcb_l + 200 * 128,
                                              RgLH, RgLL, RcLH, RcLL);
    pack_rec<<<dim3(16, 4), 256, 0, stream>>>(wgf_h + 256 * 256, wgb_h + 256 * 256,
                                              wcf_h + 256 * 128, wcb_h + 256 * 128,
                                              RgHH, RgHL, RcHH, RcHL);

    for (int c = 0; c < NCH; ++c) {
        const float* Xc = X + (size_t)c * nRows * 50 * 200;
        int Mr16 = (int)(M1 / 16);
        pack_a_frag<<<(Mr16 * 7 * 64 + 255) / 256, 256, 0, stream>>>(Xc, AXh, AXl, Mr16, 7, 200);
        mfma_gemm<<<dim3((int)(M1 / 128), 6), 256, 0, stream>>>(AXh, AXl, WLh, WLl, biasL, G1, 7, 768, 0);
        bigru_wave<<<(int)(nRows / 16) * 2, 128, 0, stream>>>(G1, RgLH, RgLL, RcLH, RcLL,
                                                              slen, low, (int)(c * nRows), 50);
        attn_fused<<<(int)nRows, 256, 0, stream>>>(low, WaLh, WaLl, ba_l, uw,
                                                   out + 66, sent + (size_t)c * nRows * 256, 50, (int)(c * nRows));
    }
    // ---- sentence level ----
    pack_a_frag<<<(160 * 8 * 64 + 255) / 256, 256, 0, stream>>>(sent, pSh, pSl, 160, 8, 256);
    mfma_gemm<<<dim3(20, 6), 256, 0, stream>>>(pSh, pSl, WHh, WHl, biasH, Gs, 8, 768, 0);
    bigru_wave<<<8, 128, 0, stream>>>(Gs, RgHH, RgHL, RcHH, RcHL, dlen, high, 0, 40);
    attn_fused<<<64, 256, 0, stream>>>(high, WaHh, WaHl, ba_h, us, out + 128066, dvec, 40, 0);
    head_kernel<<<1, 256, 0, stream>>>(dvec, wp, bp, y, wa_l, ba_l, wa_h, uw, us, out);
}

// Round 7
// 1587.498 us; speedup vs baseline: 2.5681x; 2.5681x over previous
//
#include <hip/hip_runtime.h>
#include <hip/hip_bf16.h>

// HAN_81801947119983 — round 7: revert word recurrence to R5 bigru_mfma (known-good,
// 224 µs; R6's reg-staged variant spilled: VGPR 256, +100 MB scratch writes).
// New single-wave sent_gru for the 64-row sentence recurrence (was ~180 µs on 8 blocks).
// B=64, D=40, S=50, E=200, H=128, C=10. N1=2560 word rows (T=50), 64 doc rows (T=40).
// G cols: [0:256) fw gates, [256:384) fw cand, [384:640) bw gates, [640:768) bw cand.
// MFMA 16x16x32 bf16: A frag lane holds A[m=lane&15][k=quad*8+j]; B frag B[k][n=lane&15];
// C/D col=lane&15, row=quad*4+reg.  Pack uint4 idx: ((tile*KC+kc)*4+quad)*16+(lane&15).

typedef __attribute__((ext_vector_type(8))) short short8;
typedef __attribute__((ext_vector_type(4))) float f32x4;

__device__ __forceinline__ float fsigmoid(float x) { return 1.f / (1.f + __expf(-x)); }
__device__ __forceinline__ float ftanh(float x)    { float e = __expf(2.f * x); return 1.f - 2.f / (e + 1.f); }

__device__ __forceinline__ unsigned short f2bf(float x) {
    unsigned int u = __builtin_bit_cast(unsigned int, x);
    u += 0x7fffu + ((u >> 16) & 1u);
    return (unsigned short)(u >> 16);
}
__device__ __forceinline__ float bf2f(unsigned short h) {
    unsigned int u = ((unsigned int)h) << 16;
    return __builtin_bit_cast(float, u);
}
__device__ __forceinline__ uint4 pack8(const unsigned short* v) {
    uint4 r;
    r.x = (unsigned int)v[0] | ((unsigned int)v[1] << 16);
    r.y = (unsigned int)v[2] | ((unsigned int)v[3] << 16);
    r.z = (unsigned int)v[4] | ((unsigned int)v[5] << 16);
    r.w = (unsigned int)v[6] | ((unsigned int)v[7] << 16);
    return r;
}
__device__ __forceinline__ void cvt8(const float* v, short8& hi, short8& lo) {
    unsigned short h[8], l[8];
#pragma unroll
    for (int j = 0; j < 8; ++j) {
        unsigned short hh = f2bf(v[j]);
        h[j] = hh;
        l[j] = f2bf(v[j] - bf2f(hh));
    }
    uint4 uh = pack8(h), ul = pack8(l);
    hi = __builtin_bit_cast(short8, uh);
    lo = __builtin_bit_cast(short8, ul);
}

// ---------------- weight concat: W[E,768] = [wg_f | wc_f | wg_b | wc_b], bias[768] ----------------
__global__ __launch_bounds__(256) void pack_weights(
    const float* __restrict__ wg_f, const float* __restrict__ bg_f,
    const float* __restrict__ wc_f, const float* __restrict__ bc_f,
    const float* __restrict__ wg_b, const float* __restrict__ bg_b,
    const float* __restrict__ wc_b, const float* __restrict__ bc_b,
    float* __restrict__ W, float* __restrict__ bias, int E)
{
    int idx = blockIdx.x * 256 + threadIdx.x;
    if (idx < 768) {
        int c = idx; float v;
        if (c < 256) v = bg_f[c];
        else if (c < 384) v = bc_f[c - 256];
        else if (c < 640) v = bg_b[c - 384];
        else v = bc_b[c - 640];
        bias[c] = v;
    }
    if (idx >= E * 768) return;
    int k = idx / 768, c = idx - k * 768;
    float v;
    if (c < 256) v = wg_f[k * 256 + c];
    else if (c < 384) v = wc_f[k * 128 + (c - 256)];
    else if (c < 640) v = wg_b[k * 256 + (c - 384)];
    else v = wc_b[k * 128 + (c - 640)];
    W[idx] = v;
}

// ---------------- pack A (row-major [Mr x Ks] fp32) into frag-order hi/lo bf16 ----------------
__global__ __launch_bounds__(256) void pack_a_frag(
    const float* __restrict__ src, uint4* __restrict__ dstH, uint4* __restrict__ dstL,
    int Mr16, int KC, int Ks)
{
    int idx = blockIdx.x * 256 + threadIdx.x;
    if (idx >= Mr16 * KC * 64) return;
    int lane = idx & 63;
    int g = idx >> 6;
    int mb = g / KC, kc = g - mb * KC;
    int m = lane & 15, quad = lane >> 4;
    int row = mb * 16 + m;
    int k0 = kc * 32 + quad * 8;
    const float* s = src + (size_t)row * Ks;
    unsigned short hi[8], lo[8];
#pragma unroll
    for (int j = 0; j < 8; ++j) {
        float x = (k0 + j < Ks) ? s[k0 + j] : 0.f;
        unsigned short h = f2bf(x);
        hi[j] = h;
        lo[j] = f2bf(x - bf2f(h));
    }
    dstH[idx] = pack8(hi);
    dstL[idx] = pack8(lo);
}

// ---------------- pack W (row-major [Ks x N] fp32) into frag-order hi/lo bf16 ----------------
__global__ __launch_bounds__(256) void pack_w_frag(
    const float* __restrict__ src, uint4* __restrict__ dstH, uint4* __restrict__ dstL,
    int N16, int KC, int Ks, int N)
{
    int idx = blockIdx.x * 256 + threadIdx.x;
    if (idx >= N16 * KC * 64) return;
    int lane = idx & 63;
    int g = idx >> 6;
    int nb = g / KC, kc = g - nb * KC;
    int m = lane & 15, quad = lane >> 4;
    int n = nb * 16 + m;
    int k0 = kc * 32 + quad * 8;
    unsigned short hi[8], lo[8];
#pragma unroll
    for (int j = 0; j < 8; ++j) {
        float x = (k0 + j < Ks) ? src[(size_t)(k0 + j) * N + n] : 0.f;
        unsigned short h = f2bf(x);
        hi[j] = h;
        lo[j] = f2bf(x - bf2f(h));
    }
    dstH[idx] = pack8(hi);
    dstL[idx] = pack8(lo);
}

// ---------------- merged recurrent weight pack: 4 matrices per level ----------------
__global__ __launch_bounds__(256) void pack_rec(
    const float* __restrict__ wgf, const float* __restrict__ wgb,
    const float* __restrict__ wcf, const float* __restrict__ wcb,
    uint4* __restrict__ RgH, uint4* __restrict__ RgL,
    uint4* __restrict__ RcH, uint4* __restrict__ RcL)
{
    int sel = blockIdx.y;
    const float* src; uint4 *dH, *dL; int N16, N;
    if (sel == 0)      { src = wgf; dH = RgH;        dL = RgL;        N16 = 16; N = 256; }
    else if (sel == 1) { src = wgb; dH = RgH + 4096; dL = RgL + 4096; N16 = 16; N = 256; }
    else if (sel == 2) { src = wcf; dH = RcH;        dL = RcL;        N16 = 8;  N = 128; }
    else               { src = wcb; dH = RcH + 2048; dL = RcL + 2048; N16 = 8;  N = 128; }
    int idx = blockIdx.x * 256 + threadIdx.x;
    if (idx >= N16 * 4 * 64) return;
    int lane = idx & 63;
    int g = idx >> 6;
    int nb = g / 4, kc = g - nb * 4;
    int m = lane & 15, quad = lane >> 4;
    int n = nb * 16 + m;
    int k0 = kc * 32 + quad * 8;
    unsigned short hi[8], lo[8];
#pragma unroll
    for (int j = 0; j < 8; ++j) {
        float x = src[(size_t)(k0 + j) * N + n];
        unsigned short h = f2bf(x);
        hi[j] = h;
        lo[j] = f2bf(x - bf2f(h));
    }
    dH[idx] = pack8(hi);
    dL[idx] = pack8(lo);
}

// ---------------- MFMA GEMM: C = A @ W + bias, split-bf16 3-product ----------------
__global__ __launch_bounds__(256) void mfma_gemm(
    const uint4* __restrict__ Ah, const uint4* __restrict__ Al,
    const uint4* __restrict__ Bh, const uint4* __restrict__ Bl,
    const float* __restrict__ bias, float* __restrict__ C,
    int KC, int ldc, int act)
{
    int tid = threadIdx.x;
    int lane = tid & 63;
    int w = tid >> 6;
    int wm = w >> 1, wn = w & 1;
    int quad = lane >> 4, m = lane & 15;
    int bm = blockIdx.x, bn = blockIdx.y;
    f32x4 acc[4][4];
#pragma unroll
    for (int i = 0; i < 4; ++i)
#pragma unroll
        for (int j = 0; j < 4; ++j) acc[i][j] = (f32x4){0.f, 0.f, 0.f, 0.f};

    size_t aBase[4], bBase[4];
#pragma unroll
    for (int i = 0; i < 4; ++i) {
        aBase[i] = ((size_t)(bm * 8 + wm * 4 + i) * KC) * 64 + quad * 16 + m;
        bBase[i] = ((size_t)(bn * 8 + wn * 4 + i) * KC) * 64 + quad * 16 + m;
    }
    for (int kc = 0; kc < KC; ++kc) {
        short8 ah[4], al[4], bh[4], bl[4];
#pragma unroll
        for (int i = 0; i < 4; ++i) {
            ah[i] = __builtin_bit_cast(short8, Ah[aBase[i]]);
            al[i] = __builtin_bit_cast(short8, Al[aBase[i]]);
            bh[i] = __builtin_bit_cast(short8, Bh[bBase[i]]);
            bl[i] = __builtin_bit_cast(short8, Bl[bBase[i]]);
            aBase[i] += 64; bBase[i] += 64;
        }
#pragma unroll
        for (int i = 0; i < 4; ++i)
#pragma unroll
            for (int j = 0; j < 4; ++j) {
                acc[i][j] = __builtin_amdgcn_mfma_f32_16x16x32_bf16(ah[i], bh[j], acc[i][j], 0, 0, 0);
                acc[i][j] = __builtin_amdgcn_mfma_f32_16x16x32_bf16(ah[i], bl[j], acc[i][j], 0, 0, 0);
                acc[i][j] = __builtin_amdgcn_mfma_f32_16x16x32_bf16(al[i], bh[j], acc[i][j], 0, 0, 0);
            }
    }
#pragma unroll
    for (int i = 0; i < 4; ++i) {
        int row0 = bm * 128 + wm * 64 + i * 16 + quad * 4;
#pragma unroll
        for (int j = 0; j < 4; ++j) {
            int col = bn * 128 + wn * 64 + j * 16 + m;
            float b = bias[col];
#pragma unroll
            for (int r = 0; r < 4; ++r) {
                float v = acc[i][j][r] + b;
                if (act) v = ftanh(v);
                C[(size_t)(row0 + r) * ldc + col] = v;
            }
        }
    }
}

// ---------------- MFMA BiGRU (R5 known-good): 16 rows x 1 dir per block, 4 waves ----------------
__global__ __launch_bounds__(256) void bigru_mfma(
    const float* __restrict__ G,      // [nRows*T, 768] chunk-local
    const uint4* __restrict__ WgH, const uint4* __restrict__ WgL,  // [2 dirs][16 nt][4 kc][64]
    const uint4* __restrict__ WcH, const uint4* __restrict__ WcL,  // [2 dirs][8 nt][4 kc][64]
    const int* __restrict__ lens,
    float* __restrict__ outbuf,       // [nRows*T, 256] chunk-local (zeros at invalid)
    int rowOff, int T)
{
    __shared__ float hs[16][132];
    __shared__ float zs[16][132];
    __shared__ uint4 hfH[4][64], hfL[4][64];
    __shared__ uint4 rfH[4][64], rfL[4][64];
    __shared__ int Ls[16];

    int tid = threadIdx.x;
    int dir = blockIdx.x & 1;
    int rg0 = (blockIdx.x >> 1) * 16;
    int lane = tid & 63, w = tid >> 6;
    int quad = lane >> 4, mc = lane & 15;
    for (int i = tid; i < 16 * 132; i += 256) { (&hs[0][0])[i] = 0.f; }
    for (int i = tid; i < 256; i += 256) { hfH[0][i] = (uint4){0,0,0,0}; hfL[0][i] = (uint4){0,0,0,0}; }
    if (tid < 16) Ls[tid] = lens[rowOff + rg0 + tid];
    __syncthreads();
    const int goff = dir * 384;
    unsigned short* hfHu = (unsigned short*)hfH;
    unsigned short* hfLu = (unsigned short*)hfL;
    unsigned short* rfHu = (unsigned short*)rfH;
    unsigned short* rfLu = (unsigned short*)rfL;

    for (int t = 0; t < T; ++t) {
        int Lr[4], tir[4];
#pragma unroll
        for (int r = 0; r < 4; ++r) {
            int L = Ls[quad * 4 + r];
            Lr[r] = L;
            tir[r] = dir ? ((t < L) ? (L - 1 - t) : t) : t;
        }
        // prefetch G (consumed after MFMAs)
        float gG[4][4], gC[2][4];
#pragma unroll
        for (int r = 0; r < 4; ++r) {
            const float* gbase = &G[((size_t)(rg0 + quad * 4 + r) * T + tir[r]) * 768 + goff];
#pragma unroll
            for (int i = 0; i < 4; ++i) gG[i][r] = gbase[(w * 4 + i) * 16 + mc];
#pragma unroll
            for (int i = 0; i < 2; ++i) gC[i][r] = gbase[256 + (w * 2 + i) * 16 + mc];
        }
        // gates MFMA: wave handles n-tiles w*4..w*4+3 of 16
        f32x4 ga[4];
#pragma unroll
        for (int i = 0; i < 4; ++i) ga[i] = (f32x4){0.f, 0.f, 0.f, 0.f};
#pragma unroll
        for (int kc = 0; kc < 4; ++kc) {
            short8 ah = __builtin_bit_cast(short8, hfH[kc][lane]);
            short8 al = __builtin_bit_cast(short8, hfL[kc][lane]);
#pragma unroll
            for (int i = 0; i < 4; ++i) {
                size_t idx = (((size_t)(dir * 16 + w * 4 + i) * 4 + kc) << 6) + lane;
                short8 bh = __builtin_bit_cast(short8, WgH[idx]);
                short8 bl = __builtin_bit_cast(short8, WgL[idx]);
                ga[i] = __builtin_amdgcn_mfma_f32_16x16x32_bf16(ah, bh, ga[i], 0, 0, 0);
                ga[i] = __builtin_amdgcn_mfma_f32_16x16x32_bf16(ah, bl, ga[i], 0, 0, 0);
                ga[i] = __builtin_amdgcn_mfma_f32_16x16x32_bf16(al, bh, ga[i], 0, 0, 0);
            }
        }
        // gate elementwise: rh -> rf frags (u16), z -> zs
#pragma unroll
        for (int i = 0; i < 4; ++i) {
            int n = (w * 4 + i) * 16 + mc;
#pragma unroll
            for (int r = 0; r < 4; ++r) {
                int m = quad * 4 + r;
                float s = fsigmoid(ga[i][r] + gG[i][r]);
                if (n < 128) {
                    float rh = s * hs[m][n];
                    unsigned short hi = f2bf(rh);
                    int fi = ((((n >> 5) * 64) + (((n >> 3) & 3) * 16) + m) << 3) + (n & 7);
                    rfHu[fi] = hi;
                    rfLu[fi] = f2bf(rh - bf2f(hi));
                } else {
                    zs[m][n - 128] = s;
                }
            }
        }
        __syncthreads();
        // cand MFMA: wave handles n-tiles w*2..w*2+1 of 8
        f32x4 ca[2];
#pragma unroll
        for (int i = 0; i < 2; ++i) ca[i] = (f32x4){0.f, 0.f, 0.f, 0.f};
#pragma unroll
        for (int kc = 0; kc < 4; ++kc) {
            short8 ar = __builtin_bit_cast(short8, rfH[kc][lane]);
            short8 al = __builtin_bit_cast(short8, rfL[kc][lane]);
#pragma unroll
            for (int i = 0; i < 2; ++i) {
                size_t idx = (((size_t)(dir * 8 + w * 2 + i) * 4 + kc) << 6) + lane;
                short8 bh = __builtin_bit_cast(short8, WcH[idx]);
                short8 bl = __builtin_bit_cast(short8, WcL[idx]);
                ca[i] = __builtin_amdgcn_mfma_f32_16x16x32_bf16(ar, bh, ca[i], 0, 0, 0);
                ca[i] = __builtin_amdgcn_mfma_f32_16x16x32_bf16(ar, bl, ca[i], 0, 0, 0);
                ca[i] = __builtin_amdgcn_mfma_f32_16x16x32_bf16(al, bh, ca[i], 0, 0, 0);
            }
        }
        // update: h' = z*h + (1-z)*cand; refresh fp32 + bf16 mirrors; write out
#pragma unroll
        for (int i = 0; i < 2; ++i) {
            int n = (w * 2 + i) * 16 + mc;
            int fi0 = ((((n >> 5) * 64) + (((n >> 3) & 3) * 16)) << 3) + (n & 7);
#pragma unroll
            for (int r = 0; r < 4; ++r) {
                int m = quad * 4 + r;
                bool valid = (t < Lr[r]);
                float cd = ftanh(ca[i][r] + gC[i][r]);
                float z = zs[m][n];
                float h = hs[m][n];
                float hn = z * h + (1.f - z) * cd;
                float ov = valid ? hn : 0.f;
                if (valid) {
                    hs[m][n] = hn;
                    unsigned short hi = f2bf(hn);
                    int fi = fi0 + (m << 3);
                    hfHu[fi] = hi;
                    hfLu[fi] = f2bf(hn - bf2f(hi));
                }
                outbuf[((size_t)(rg0 + m) * T + tir[r]) * 256 + dir * 128 + n] = ov;
            }
        }
        __syncthreads();
    }
}

// ---------------- single-wave sentence GRU: 128 blocks = 64 rows x 2 dirs ----------------
// h in LDS; fp32 matvec streaming original h-part weights from L2 (196 KB working set,
// L2-resident). Single-wave barriers are cheap; per-step critical path ~2k cyc.
__global__ __launch_bounds__(64) void sent_gru(
    const float* __restrict__ Gs,    // [64*40, 768]
    const float* __restrict__ WgF, const float* __restrict__ WcF,  // h-part [128,256]/[128,128]
    const float* __restrict__ WgB, const float* __restrict__ WcB,
    const int* __restrict__ dlen,
    float* __restrict__ high)        // [64*40, 256] (zeros at invalid)
{
    __shared__ float hv[128], rhv[128], zv[128];
    int b = blockIdx.x;
    int dir = b >> 6, n = b & 63;
    int lane = threadIdx.x;
    const float* Wg = dir ? WgB : WgF;
    const float* Wc = dir ? WcB : WcF;
    int L = dlen[n];
    for (int i = lane; i < 128; i += 64) hv[i] = 0.f;
    __syncthreads();
    int j0 = lane * 4;   // gate cols
    int c0 = lane * 2;   // cand/update cols
    for (int t = 0; t < 40; ++t) {
        bool valid = (t < L);
        int ti = (dir && valid) ? (L - 1 - t) : t;
        const float* Grow = &Gs[((size_t)n * 40 + ti) * 768 + dir * 384];
        // gates: 4 cols/lane, K=128
        float4 acc = *(const float4*)&Grow[j0];
        for (int k = 0; k < 128; k += 4) {
            float4 h4 = *(const float4*)&hv[k];
            const float* wp = &Wg[(size_t)k * 256 + j0];
            float4 w0 = *(const float4*)(wp);
            float4 w1 = *(const float4*)(wp + 256);
            float4 w2 = *(const float4*)(wp + 512);
            float4 w3 = *(const float4*)(wp + 768);
            acc.x += h4.x * w0.x + h4.y * w1.x + h4.z * w2.x + h4.w * w3.x;
            acc.y += h4.x * w0.y + h4.y * w1.y + h4.z * w2.y + h4.w * w3.y;
            acc.z += h4.x * w0.z + h4.y * w1.z + h4.z * w2.z + h4.w * w3.z;
            acc.w += h4.x * w0.w + h4.y * w1.w + h4.z * w2.w + h4.w * w3.w;
        }
        float4 s4;
        s4.x = fsigmoid(acc.x); s4.y = fsigmoid(acc.y);
        s4.z = fsigmoid(acc.z); s4.w = fsigmoid(acc.w);
        if (lane < 32) {
            float4 ho = *(const float4*)&hv[j0];
            float4 p;
            p.x = s4.x * ho.x; p.y = s4.y * ho.y; p.z = s4.z * ho.z; p.w = s4.w * ho.w;
            *(float4*)&rhv[j0] = p;
        } else {
            *(float4*)&zv[j0 - 128] = s4;
        }
        __syncthreads();
        // cand: 2 cols/lane, K=128
        float ax = Grow[256 + c0], ay = Grow[256 + c0 + 1];
        for (int k = 0; k < 128; k += 4) {
            float4 r4 = *(const float4*)&rhv[k];
            const float* wp = &Wc[(size_t)k * 128 + c0];
            float2 w0 = *(const float2*)(wp);
            float2 w1 = *(const float2*)(wp + 128);
            float2 w2 = *(const float2*)(wp + 256);
            float2 w3 = *(const float2*)(wp + 384);
            ax += r4.x * w0.x + r4.y * w1.x + r4.z * w2.x + r4.w * w3.x;
            ay += r4.x * w0.y + r4.y * w1.y + r4.z * w2.y + r4.w * w3.y;
        }
        float cx = ftanh(ax), cy = ftanh(ay);
        float z0 = zv[c0], z1 = zv[c0 + 1];
        float h0 = hv[c0], h1 = hv[c0 + 1];
        float hn0 = z0 * h0 + (1.f - z0) * cx;
        float hn1 = z1 * h1 + (1.f - z1) * cy;
        __syncthreads();
        if (valid) { hv[c0] = hn0; hv[c0 + 1] = hn1; }
        float2 ov;
        ov.x = valid ? hn0 : 0.f;
        ov.y = valid ? hn1 : 0.f;
        *(float2*)&high[((size_t)n * 40 + ti) * 256 + dir * 128 + c0] = ov;
        __syncthreads();
    }
}

// ---------------- fused attention: proj MFMA + score + softmax + weighted sum ----------------
__global__ __launch_bounds__(256) void attn_fused(
    const float* __restrict__ outv,   // [n*T, 256]
    const uint4* __restrict__ WaH, const uint4* __restrict__ WaL,  // [8 nt][8 kc][64]
    const float* __restrict__ ba, const float* __restrict__ u,
    float* __restrict__ att_out,      // rows (attRowOff+n)*T
    float* __restrict__ vec,          // [n, 256]
    int T, int attRowOff)
{
    __shared__ float lowS[50][260];
    __shared__ float scoreS[64];
    __shared__ float attS[64];
    int n = blockIdx.x;
    int tid = threadIdx.x;
    int lane = tid & 63, w = tid >> 6;
    int quad = lane >> 4, mc = lane & 15;

    const float4* src4 = (const float4*)(outv + (size_t)n * T * 256);
    for (int idx = tid; idx < T * 64; idx += 256) {
        int row = idx >> 6, c4 = idx & 63;
        float4 v = src4[idx];
        *(float4*)&lowS[row][c4 * 4] = v;
    }
    __syncthreads();

    f32x4 acc[8];
#pragma unroll
    for (int j = 0; j < 8; ++j) acc[j] = (f32x4){0.f, 0.f, 0.f, 0.f};
    int rowA = w * 16 + mc;
    bool rowValid = rowA < T;
#pragma unroll
    for (int kc = 0; kc < 8; ++kc) {
        float v[8];
        if (rowValid) {
            const float* p = &lowS[rowA][kc * 32 + quad * 8];
#pragma unroll
            for (int j = 0; j < 8; ++j) v[j] = p[j];
        } else {
#pragma unroll
            for (int j = 0; j < 8; ++j) v[j] = 0.f;
        }
        short8 ah, al;
        cvt8(v, ah, al);
#pragma unroll
        for (int nt = 0; nt < 8; ++nt) {
            size_t idx = (((size_t)nt * 8 + kc) << 6) + lane;
            short8 bh = __builtin_bit_cast(short8, WaH[idx]);
            short8 bl = __builtin_bit_cast(short8, WaL[idx]);
            acc[nt] = __builtin_amdgcn_mfma_f32_16x16x32_bf16(ah, bh, acc[nt], 0, 0, 0);
            acc[nt] = __builtin_amdgcn_mfma_f32_16x16x32_bf16(ah, bl, acc[nt], 0, 0, 0);
            acc[nt] = __builtin_amdgcn_mfma_f32_16x16x32_bf16(al, bh, acc[nt], 0, 0, 0);
        }
    }
    float sc[4] = {0.f, 0.f, 0.f, 0.f};
#pragma unroll
    for (int nt = 0; nt < 8; ++nt) {
        int col = nt * 16 + mc;
        float bb = ba[col], uu = u[col];
#pragma unroll
        for (int r = 0; r < 4; ++r)
            sc[r] += ftanh(acc[nt][r] + bb) * uu;
    }
#pragma unroll
    for (int off = 1; off < 16; off <<= 1) {
#pragma unroll
        for (int r = 0; r < 4; ++r) sc[r] += __shfl_xor(sc[r], off);
    }
    if (mc == 0) {
#pragma unroll
        for (int r = 0; r < 4; ++r) scoreS[w * 16 + quad * 4 + r] = sc[r];
    }
    __syncthreads();
    if (w == 0) {
        float s = (lane < T) ? scoreS[lane] : -3.402823466e38f;
        float m = s;
#pragma unroll
        for (int off = 1; off < 64; off <<= 1) m = fmaxf(m, __shfl_xor(m, off));
        float e = (lane < T) ? __expf(s - m) : 0.f;
        float sum = e;
#pragma unroll
        for (int off = 1; off < 64; off <<= 1) sum += __shfl_xor(sum, off);
        float att = e / sum;
        attS[lane] = att;
        if (lane < T) att_out[(size_t)(attRowOff + n) * T + lane] = att;
    }
    __syncthreads();
    float a = 0.f;
    for (int t = 0; t < T; ++t) a += attS[t] * lowS[t][tid];
    vec[(size_t)n * 256 + tid] = a;
}

// ---------------- head: logits, log-softmax, loss(+reg), predict, accuracy ----------------
__global__ __launch_bounds__(256) void head_kernel(
    const float* __restrict__ dvec, const float* __restrict__ wp, const float* __restrict__ bp,
    const int* __restrict__ y,
    const float* __restrict__ wa_l, const float* __restrict__ ba_l, const float* __restrict__ wa_h,
    const float* __restrict__ uw, const float* __restrict__ us,
    float* __restrict__ out)
{
    __shared__ float lg[64][10];
    __shared__ float red[256];
    int tid = threadIdx.x;
    for (int idx = tid; idx < 640; idx += 256) {
        int r = idx / 10, c = idx % 10;
        float a = bp[c];
        const float* dv = dvec + r * 256;
        for (int k = 0; k < 256; ++k) a += dv[k] * wp[k * 10 + c];
        lg[r][c] = a;
    }
    __syncthreads();
    float lossv = 0.f, corr = 0.f;
    if (tid < 64) {
        float m = lg[tid][0]; int arg = 0;
        for (int c = 1; c < 10; ++c) if (lg[tid][c] > m) { m = lg[tid][c]; arg = c; }
        float se = 0.f;
        for (int c = 0; c < 10; ++c) se += __expf(lg[tid][c] - m);
        float lse = m + __logf(se);
        int yy = y[tid];
        lossv = -(lg[tid][yy] - lse);
        corr = (yy == arg) ? 1.f : 0.f;
        out[1 + tid] = (float)arg;
    }
    float rs = 0.f;
    for (int i = tid; i < 32768; i += 256) {
        float v = wa_l[i]; rs += v * v;
        float w = wa_h[i]; rs += 2.f * w * w;
    }
    if (tid < 128) {
        float v1 = ba_l[tid], v2 = uw[tid], v3 = us[tid];
        rs += v1 * v1 + v2 * v2 + v3 * v3;
    }
    red[tid] = lossv; __syncthreads();
    for (int o = 128; o > 0; o >>= 1) { if (tid < o) red[tid] += red[tid + o]; __syncthreads(); }
    float totLoss = red[0]; __syncthreads();
    red[tid] = corr; __syncthreads();
    for (int o = 128; o > 0; o >>= 1) { if (tid < o) red[tid] += red[tid + o]; __syncthreads(); }
    float totCorr = red[0]; __syncthreads();
    red[tid] = rs; __syncthreads();
    for (int o = 128; o > 0; o >>= 1) { if (tid < o) red[tid] += red[tid + o]; __syncthreads(); }
    float totReg = red[0];
    if (tid == 0) {
        out[0] = totLoss / 64.f + 0.01f * totReg;
        out[65] = totCorr / 64.f;
    }
}

extern "C" void kernel_launch(void* const* d_in, const int* in_sizes, int n_in,
                              void* d_out, int out_size, void* d_ws, size_t ws_size,
                              hipStream_t stream)
{
    const float* X    = (const float*)d_in[0];
    const int*   y    = (const int*)d_in[1];
    const int*   slen = (const int*)d_in[2];
    const int*   dlen = (const int*)d_in[3];
    const float* wgf_l = (const float*)d_in[6];
    const float* bgf_l = (const float*)d_in[7];
    const float* wcf_l = (const float*)d_in[8];
    const float* bcf_l = (const float*)d_in[9];
    const float* wgb_l = (const float*)d_in[10];
    const float* bgb_l = (const float*)d_in[11];
    const float* wcb_l = (const float*)d_in[12];
    const float* bcb_l = (const float*)d_in[13];
    const float* wa_l  = (const float*)d_in[14];
    const float* ba_l  = (const float*)d_in[15];
    const float* wgf_h = (const float*)d_in[16];
    const float* bgf_h = (const float*)d_in[17];
    const float* wcf_h = (const float*)d_in[18];
    const float* bcf_h = (const float*)d_in[19];
    const float* wgb_h = (const float*)d_in[20];
    const float* bgb_h = (const float*)d_in[21];
    const float* wcb_h = (const float*)d_in[22];
    const float* bcb_h = (const float*)d_in[23];
    const float* wa_h  = (const float*)d_in[24];
    const float* ba_h  = (const float*)d_in[25];
    const float* uw    = (const float*)d_in[26];
    const float* us    = (const float*)d_in[27];
    const float* wp    = (const float*)d_in[28];
    const float* bp    = (const float*)d_in[29];
    float* out = (float*)d_out;

    int NCH = 1;
    while (NCH < 8) {
        size_t M1t = 128000ull / NCH;
        size_t needB = (M1t * 1248ull + 5200000ull) * 4ull;
        if (needB <= ws_size) break;
        NCH *= 2;
    }
    size_t nRows = 2560 / NCH;
    size_t M1 = nRows * 50;

    float* G1     = (float*)d_ws;            // M1*768
    float* low    = G1 + M1 * 768;           // M1*256
    float* AXf    = low + M1 * 256;          // M1*224
    float* sent   = AXf + M1 * 224;          // 655360
    float* Gs     = sent + 655360;           // 1966080
    float* high   = Gs + 1966080;            // 655360
    float* dvec   = high + 655360;           // 16384
    float* pSf    = dvec + 16384;            // 655360
    float* WpackL = pSf + 655360;            // 153600
    float* biasL  = WpackL + 153600;         // 768
    float* WLf    = biasL + 768;             // 172032
    float* WpackH = WLf + 172032;            // 196608
    float* biasH  = WpackH + 196608;         // 768
    float* WHf    = biasH + 768;             // 196608
    float* WaLf   = WHf + 196608;            // 32768
    float* WaHf   = WaLf + 32768;            // 32768
    float* RgLf   = WaHf + 32768;            // 65536
    float* RcLf   = RgLf + 65536;            // 32768

    uint4* AXh = (uint4*)AXf;           uint4* AXl = (uint4*)(AXf + M1 * 112);
    uint4* pSh = (uint4*)pSf;           uint4* pSl = (uint4*)(pSf + 327680);
    uint4* WLh = (uint4*)WLf;           uint4* WLl = (uint4*)(WLf + 86016);
    uint4* WHh = (uint4*)WHf;           uint4* WHl = (uint4*)(WHf + 98304);
    uint4* WaLh = (uint4*)WaLf;         uint4* WaLl = (uint4*)(WaLf + 16384);
    uint4* WaHh = (uint4*)WaHf;         uint4* WaHl = (uint4*)(WaHf + 16384);
    uint4* RgLH = (uint4*)RgLf;         uint4* RgLL = (uint4*)(RgLf + 32768);
    uint4* RcLH = (uint4*)RcLf;         uint4* RcLL = (uint4*)(RcLf + 16384);

    pack_weights<<<600, 256, 0, stream>>>(wgf_l, bgf_l, wcf_l, bcf_l, wgb_l, bgb_l, wcb_l, bcb_l,
                                          WpackL, biasL, 200);
    pack_weights<<<768, 256, 0, stream>>>(wgf_h, bgf_h, wcf_h, bcf_h, wgb_h, bgb_h, wcb_h, bcb_h,
                                          WpackH, biasH, 256);
    pack_w_frag<<<84, 256, 0, stream>>>(WpackL, WLh, WLl, 48, 7, 200, 768);
    pack_w_frag<<<96, 256, 0, stream>>>(WpackH, WHh, WHl, 48, 8, 256, 768);
    pack_w_frag<<<16, 256, 0, stream>>>(wa_l, WaLh, WaLl, 8, 8, 256, 128);
    pack_w_frag<<<16, 256, 0, stream>>>(wa_h, WaHh, WaHl, 8, 8, 256, 128);
    pack_rec<<<dim3(16, 4), 256, 0, stream>>>(wgf_l + 200 * 256, wgb_l + 200 * 256,
                                              wcf_l + 200 * 128, wcb_l + 200 * 128,
                                              RgLH, RgLL, RcLH, RcLL);

    for (int c = 0; c < NCH; ++c) {
        const float* Xc = X + (size_t)c * nRows * 50 * 200;
        int Mr16 = (int)(M1 / 16);
        pack_a_frag<<<(Mr16 * 7 * 64 + 255) / 256, 256, 0, stream>>>(Xc, AXh, AXl, Mr16, 7, 200);
        mfma_gemm<<<dim3((int)(M1 / 128), 6), 256, 0, stream>>>(AXh, AXl, WLh, WLl, biasL, G1, 7, 768, 0);
        bigru_mfma<<<(int)(nRows / 16) * 2, 256, 0, stream>>>(G1, RgLH, RgLL, RcLH, RcLL,
                                                              slen, low, (int)(c * nRows), 50);
        attn_fused<<<(int)nRows, 256, 0, stream>>>(low, WaLh, WaLl, ba_l, uw,
                                                   out + 66, sent + (size_t)c * nRows * 256, 50, (int)(c * nRows));
    }
    // ---- sentence level ----
    pack_a_frag<<<(160 * 8 * 64 + 255) / 256, 256, 0, stream>>>(sent, pSh, pSl, 160, 8, 256);
    mfma_gemm<<<dim3(20, 6), 256, 0, stream>>>(pSh, pSl, WHh, WHl, biasH, Gs, 8, 768, 0);
    sent_gru<<<128, 64, 0, stream>>>(Gs, wgf_h + 256 * 256, wcf_h + 256 * 128,
                                     wgb_h + 256 * 256, wcb_h + 256 * 128, dlen, high);
    attn_fused<<<64, 256, 0, stream>>>(high, WaHh, WaHl, ba_h, us, out + 128066, dvec, 40, 0);
    head_kernel<<<1, 256, 0, stream>>>(dvec, wp, bp, y, wa_l, ba_l, wa_h, uw, us, out);
}

// Round 8
// 1276.133 us; speedup vs baseline: 3.1947x; 1.2440x over previous
//
#include <hip/hip_runtime.h>
#include <hip/hip_bf16.h>

// HAN_81801947119983 — round 8: bigru_mfma with one-step G prefetch + split MFMA chains;
// sentence recurrence reverted to bigru_mfma (R7's single-wave sent_gru was latency-bound
// at 510 µs: 1 wave/block cannot pipeline L2 weight streaming).
// B=64, D=40, S=50, E=200, H=128, C=10. N1=2560 word rows (T=50), 64 doc rows (T=40).
// G cols: [0:256) fw gates, [256:384) fw cand, [384:640) bw gates, [640:768) bw cand.
// MFMA 16x16x32 bf16: A frag lane holds A[m=lane&15][k=quad*8+j]; B frag B[k][n=lane&15];
// C/D col=lane&15, row=quad*4+reg.  Pack uint4 idx: ((tile*KC+kc)*4+quad)*16+(lane&15).

typedef __attribute__((ext_vector_type(8))) short short8;
typedef __attribute__((ext_vector_type(4))) float f32x4;

__device__ __forceinline__ float fsigmoid(float x) { return 1.f / (1.f + __expf(-x)); }
__device__ __forceinline__ float ftanh(float x)    { float e = __expf(2.f * x); return 1.f - 2.f / (e + 1.f); }

__device__ __forceinline__ unsigned short f2bf(float x) {
    unsigned int u = __builtin_bit_cast(unsigned int, x);
    u += 0x7fffu + ((u >> 16) & 1u);
    return (unsigned short)(u >> 16);
}
__device__ __forceinline__ float bf2f(unsigned short h) {
    unsigned int u = ((unsigned int)h) << 16;
    return __builtin_bit_cast(float, u);
}
__device__ __forceinline__ uint4 pack8(const unsigned short* v) {
    uint4 r;
    r.x = (unsigned int)v[0] | ((unsigned int)v[1] << 16);
    r.y = (unsigned int)v[2] | ((unsigned int)v[3] << 16);
    r.z = (unsigned int)v[4] | ((unsigned int)v[5] << 16);
    r.w = (unsigned int)v[6] | ((unsigned int)v[7] << 16);
    return r;
}
__device__ __forceinline__ void cvt8(const float* v, short8& hi, short8& lo) {
    unsigned short h[8], l[8];
#pragma unroll
    for (int j = 0; j < 8; ++j) {
        unsigned short hh = f2bf(v[j]);
        h[j] = hh;
        l[j] = f2bf(v[j] - bf2f(hh));
    }
    uint4 uh = pack8(h), ul = pack8(l);
    hi = __builtin_bit_cast(short8, uh);
    lo = __builtin_bit_cast(short8, ul);
}

// ---------------- weight concat: W[E,768] = [wg_f | wc_f | wg_b | wc_b], bias[768] ----------------
__global__ __launch_bounds__(256) void pack_weights(
    const float* __restrict__ wg_f, const float* __restrict__ bg_f,
    const float* __restrict__ wc_f, const float* __restrict__ bc_f,
    const float* __restrict__ wg_b, const float* __restrict__ bg_b,
    const float* __restrict__ wc_b, const float* __restrict__ bc_b,
    float* __restrict__ W, float* __restrict__ bias, int E)
{
    int idx = blockIdx.x * 256 + threadIdx.x;
    if (idx < 768) {
        int c = idx; float v;
        if (c < 256) v = bg_f[c];
        else if (c < 384) v = bc_f[c - 256];
        else if (c < 640) v = bg_b[c - 384];
        else v = bc_b[c - 640];
        bias[c] = v;
    }
    if (idx >= E * 768) return;
    int k = idx / 768, c = idx - k * 768;
    float v;
    if (c < 256) v = wg_f[k * 256 + c];
    else if (c < 384) v = wc_f[k * 128 + (c - 256)];
    else if (c < 640) v = wg_b[k * 256 + (c - 384)];
    else v = wc_b[k * 128 + (c - 640)];
    W[idx] = v;
}

// ---------------- pack A (row-major [Mr x Ks] fp32) into frag-order hi/lo bf16 ----------------
__global__ __launch_bounds__(256) void pack_a_frag(
    const float* __restrict__ src, uint4* __restrict__ dstH, uint4* __restrict__ dstL,
    int Mr16, int KC, int Ks)
{
    int idx = blockIdx.x * 256 + threadIdx.x;
    if (idx >= Mr16 * KC * 64) return;
    int lane = idx & 63;
    int g = idx >> 6;
    int mb = g / KC, kc = g - mb * KC;
    int m = lane & 15, quad = lane >> 4;
    int row = mb * 16 + m;
    int k0 = kc * 32 + quad * 8;
    const float* s = src + (size_t)row * Ks;
    unsigned short hi[8], lo[8];
#pragma unroll
    for (int j = 0; j < 8; ++j) {
        float x = (k0 + j < Ks) ? s[k0 + j] : 0.f;
        unsigned short h = f2bf(x);
        hi[j] = h;
        lo[j] = f2bf(x - bf2f(h));
    }
    dstH[idx] = pack8(hi);
    dstL[idx] = pack8(lo);
}

// ---------------- pack W (row-major [Ks x N] fp32) into frag-order hi/lo bf16 ----------------
__global__ __launch_bounds__(256) void pack_w_frag(
    const float* __restrict__ src, uint4* __restrict__ dstH, uint4* __restrict__ dstL,
    int N16, int KC, int Ks, int N)
{
    int idx = blockIdx.x * 256 + threadIdx.x;
    if (idx >= N16 * KC * 64) return;
    int lane = idx & 63;
    int g = idx >> 6;
    int nb = g / KC, kc = g - nb * KC;
    int m = lane & 15, quad = lane >> 4;
    int n = nb * 16 + m;
    int k0 = kc * 32 + quad * 8;
    unsigned short hi[8], lo[8];
#pragma unroll
    for (int j = 0; j < 8; ++j) {
        float x = (k0 + j < Ks) ? src[(size_t)(k0 + j) * N + n] : 0.f;
        unsigned short h = f2bf(x);
        hi[j] = h;
        lo[j] = f2bf(x - bf2f(h));
    }
    dstH[idx] = pack8(hi);
    dstL[idx] = pack8(lo);
}

// ---------------- merged recurrent weight pack: 4 matrices per level ----------------
__global__ __launch_bounds__(256) void pack_rec(
    const float* __restrict__ wgf, const float* __restrict__ wgb,
    const float* __restrict__ wcf, const float* __restrict__ wcb,
    uint4* __restrict__ RgH, uint4* __restrict__ RgL,
    uint4* __restrict__ RcH, uint4* __restrict__ RcL)
{
    int sel = blockIdx.y;
    const float* src; uint4 *dH, *dL; int N16, N;
    if (sel == 0)      { src = wgf; dH = RgH;        dL = RgL;        N16 = 16; N = 256; }
    else if (sel == 1) { src = wgb; dH = RgH + 4096; dL = RgL + 4096; N16 = 16; N = 256; }
    else if (sel == 2) { src = wcf; dH = RcH;        dL = RcL;        N16 = 8;  N = 128; }
    else               { src = wcb; dH = RcH + 2048; dL = RcL + 2048; N16 = 8;  N = 128; }
    int idx = blockIdx.x * 256 + threadIdx.x;
    if (idx >= N16 * 4 * 64) return;
    int lane = idx & 63;
    int g = idx >> 6;
    int nb = g / 4, kc = g - nb * 4;
    int m = lane & 15, quad = lane >> 4;
    int n = nb * 16 + m;
    int k0 = kc * 32 + quad * 8;
    unsigned short hi[8], lo[8];
#pragma unroll
    for (int j = 0; j < 8; ++j) {
        float x = src[(size_t)(k0 + j) * N + n];
        unsigned short h = f2bf(x);
        hi[j] = h;
        lo[j] = f2bf(x - bf2f(h));
    }
    dH[idx] = pack8(hi);
    dL[idx] = pack8(lo);
}

// ---------------- MFMA GEMM: C = A @ W + bias, split-bf16 3-product ----------------
__global__ __launch_bounds__(256) void mfma_gemm(
    const uint4* __restrict__ Ah, const uint4* __restrict__ Al,
    const uint4* __restrict__ Bh, const uint4* __restrict__ Bl,
    const float* __restrict__ bias, float* __restrict__ C,
    int KC, int ldc, int act)
{
    int tid = threadIdx.x;
    int lane = tid & 63;
    int w = tid >> 6;
    int wm = w >> 1, wn = w & 1;
    int quad = lane >> 4, m = lane & 15;
    int bm = blockIdx.x, bn = blockIdx.y;
    f32x4 acc[4][4];
#pragma unroll
    for (int i = 0; i < 4; ++i)
#pragma unroll
        for (int j = 0; j < 4; ++j) acc[i][j] = (f32x4){0.f, 0.f, 0.f, 0.f};

    size_t aBase[4], bBase[4];
#pragma unroll
    for (int i = 0; i < 4; ++i) {
        aBase[i] = ((size_t)(bm * 8 + wm * 4 + i) * KC) * 64 + quad * 16 + m;
        bBase[i] = ((size_t)(bn * 8 + wn * 4 + i) * KC) * 64 + quad * 16 + m;
    }
    for (int kc = 0; kc < KC; ++kc) {
        short8 ah[4], al[4], bh[4], bl[4];
#pragma unroll
        for (int i = 0; i < 4; ++i) {
            ah[i] = __builtin_bit_cast(short8, Ah[aBase[i]]);
            al[i] = __builtin_bit_cast(short8, Al[aBase[i]]);
            bh[i] = __builtin_bit_cast(short8, Bh[bBase[i]]);
            bl[i] = __builtin_bit_cast(short8, Bl[bBase[i]]);
            aBase[i] += 64; bBase[i] += 64;
        }
#pragma unroll
        for (int i = 0; i < 4; ++i)
#pragma unroll
            for (int j = 0; j < 4; ++j) {
                acc[i][j] = __builtin_amdgcn_mfma_f32_16x16x32_bf16(ah[i], bh[j], acc[i][j], 0, 0, 0);
                acc[i][j] = __builtin_amdgcn_mfma_f32_16x16x32_bf16(ah[i], bl[j], acc[i][j], 0, 0, 0);
                acc[i][j] = __builtin_amdgcn_mfma_f32_16x16x32_bf16(al[i], bh[j], acc[i][j], 0, 0, 0);
            }
    }
#pragma unroll
    for (int i = 0; i < 4; ++i) {
        int row0 = bm * 128 + wm * 64 + i * 16 + quad * 4;
#pragma unroll
        for (int j = 0; j < 4; ++j) {
            int col = bn * 128 + wn * 64 + j * 16 + m;
            float b = bias[col];
#pragma unroll
            for (int r = 0; r < 4; ++r) {
                float v = acc[i][j][r] + b;
                if (act) v = ftanh(v);
                C[(size_t)(row0 + r) * ldc + col] = v;
            }
        }
    }
}

// ---------------- MFMA BiGRU v5: 16 rows x 1 dir per block, 4 waves ----------------
// R5 structure + (1) G prefetched one full step ahead (plain global->VGPR loads wait at
// first USE, not at barriers -> full-step latency cover) and (2) MFMA chains split in two
// (6-deep instead of 12-deep dependent chains).
__global__ __launch_bounds__(256) void bigru_mfma(
    const float* __restrict__ G,      // [nRows*T, 768] chunk-local
    const uint4* __restrict__ WgH, const uint4* __restrict__ WgL,  // [2 dirs][16 nt][4 kc][64]
    const uint4* __restrict__ WcH, const uint4* __restrict__ WcL,  // [2 dirs][8 nt][4 kc][64]
    const int* __restrict__ lens,
    float* __restrict__ outbuf,       // [nRows*T, 256] chunk-local (zeros at invalid)
    int rowOff, int T)
{
    __shared__ float hs[16][132];
    __shared__ float zs[16][132];
    __shared__ uint4 hfH[4][64], hfL[4][64];
    __shared__ uint4 rfH[4][64], rfL[4][64];

    int tid = threadIdx.x;
    int dir = blockIdx.x & 1;
    int rg0 = (blockIdx.x >> 1) * 16;
    int lane = tid & 63, w = tid >> 6;
    int quad = lane >> 4, mc = lane & 15;
    for (int i = tid; i < 16 * 132; i += 256) { (&hs[0][0])[i] = 0.f; }
    if (tid < 256) { hfH[0][tid] = (uint4){0,0,0,0}; hfL[0][tid] = (uint4){0,0,0,0}; }
    const int goff = dir * 384;
    unsigned short* hfHu = (unsigned short*)hfH;
    unsigned short* hfLu = (unsigned short*)hfL;
    unsigned short* rfHu = (unsigned short*)rfH;
    unsigned short* rfLu = (unsigned short*)rfL;

    int Lr[4];
#pragma unroll
    for (int r = 0; r < 4; ++r) Lr[r] = lens[rowOff + rg0 + quad * 4 + r];

    // prefetch state for current step
    float gG[4][4], gC[2][4];
    int tir[4];
#pragma unroll
    for (int r = 0; r < 4; ++r) {
        tir[r] = dir ? ((0 < Lr[r]) ? (Lr[r] - 1) : 0) : 0;
        const float* gbase = &G[((size_t)(rg0 + quad * 4 + r) * T + tir[r]) * 768 + goff];
#pragma unroll
        for (int i = 0; i < 4; ++i) gG[i][r] = gbase[(w * 4 + i) * 16 + mc];
#pragma unroll
        for (int i = 0; i < 2; ++i) gC[i][r] = gbase[256 + (w * 2 + i) * 16 + mc];
    }
    __syncthreads();

    for (int t = 0; t < T; ++t) {
        // (a) issue next step's G loads — consumed a full step from now
        float gGn[4][4], gCn[2][4];
        int tirn[4];
        if (t + 1 < T) {
#pragma unroll
            for (int r = 0; r < 4; ++r) {
                int t1 = t + 1;
                tirn[r] = dir ? ((t1 < Lr[r]) ? (Lr[r] - 1 - t1) : t1) : t1;
                const float* gbase = &G[((size_t)(rg0 + quad * 4 + r) * T + tirn[r]) * 768 + goff];
#pragma unroll
                for (int i = 0; i < 4; ++i) gGn[i][r] = gbase[(w * 4 + i) * 16 + mc];
#pragma unroll
                for (int i = 0; i < 2; ++i) gCn[i][r] = gbase[256 + (w * 2 + i) * 16 + mc];
            }
        }
        // (b) gates MFMA: wave handles n-tiles w*4..w*4+3; split chains (kc 0-1 / 2-3)
        f32x4 ga[4], gb[4];
#pragma unroll
        for (int i = 0; i < 4; ++i) { ga[i] = (f32x4){0.f,0.f,0.f,0.f}; gb[i] = (f32x4){0.f,0.f,0.f,0.f}; }
#pragma unroll
        for (int kc = 0; kc < 4; ++kc) {
            short8 ah = __builtin_bit_cast(short8, hfH[kc][lane]);
            short8 al = __builtin_bit_cast(short8, hfL[kc][lane]);
#pragma unroll
            for (int i = 0; i < 4; ++i) {
                size_t idx = (((size_t)(dir * 16 + w * 4 + i) * 4 + kc) << 6) + lane;
                short8 bh = __builtin_bit_cast(short8, WgH[idx]);
                short8 bl = __builtin_bit_cast(short8, WgL[idx]);
                if (kc < 2) {
                    ga[i] = __builtin_amdgcn_mfma_f32_16x16x32_bf16(ah, bh, ga[i], 0, 0, 0);
                    ga[i] = __builtin_amdgcn_mfma_f32_16x16x32_bf16(ah, bl, ga[i], 0, 0, 0);
                    ga[i] = __builtin_amdgcn_mfma_f32_16x16x32_bf16(al, bh, ga[i], 0, 0, 0);
                } else {
                    gb[i] = __builtin_amdgcn_mfma_f32_16x16x32_bf16(ah, bh, gb[i], 0, 0, 0);
                    gb[i] = __builtin_amdgcn_mfma_f32_16x16x32_bf16(ah, bl, gb[i], 0, 0, 0);
                    gb[i] = __builtin_amdgcn_mfma_f32_16x16x32_bf16(al, bh, gb[i], 0, 0, 0);
                }
            }
        }
        // (c) gate elementwise: rh -> rf frags, z -> zs
#pragma unroll
        for (int i = 0; i < 4; ++i) {
            int n = (w * 4 + i) * 16 + mc;
#pragma unroll
            for (int r = 0; r < 4; ++r) {
                int m = quad * 4 + r;
                float s = fsigmoid(ga[i][r] + gb[i][r] + gG[i][r]);
                if (n < 128) {
                    float rh = s * hs[m][n];
                    unsigned short hi = f2bf(rh);
                    int fi = ((((n >> 5) * 64) + (((n >> 3) & 3) * 16) + m) << 3) + (n & 7);
                    rfHu[fi] = hi;
                    rfLu[fi] = f2bf(rh - bf2f(hi));
                } else {
                    zs[m][n - 128] = s;
                }
            }
        }
        __syncthreads();
        // (d) cand MFMA: wave handles n-tiles w*2..w*2+1; split chains
        f32x4 ca[2], cb[2];
#pragma unroll
        for (int i = 0; i < 2; ++i) { ca[i] = (f32x4){0.f,0.f,0.f,0.f}; cb[i] = (f32x4){0.f,0.f,0.f,0.f}; }
#pragma unroll
        for (int kc = 0; kc < 4; ++kc) {
            short8 ar = __builtin_bit_cast(short8, rfH[kc][lane]);
            short8 al = __builtin_bit_cast(short8, rfL[kc][lane]);
#pragma unroll
            for (int i = 0; i < 2; ++i) {
                size_t idx = (((size_t)(dir * 8 + w * 2 + i) * 4 + kc) << 6) + lane;
                short8 bh = __builtin_bit_cast(short8, WcH[idx]);
                short8 bl = __builtin_bit_cast(short8, WcL[idx]);
                if (kc < 2) {
                    ca[i] = __builtin_amdgcn_mfma_f32_16x16x32_bf16(ar, bh, ca[i], 0, 0, 0);
                    ca[i] = __builtin_amdgcn_mfma_f32_16x16x32_bf16(ar, bl, ca[i], 0, 0, 0);
                    ca[i] = __builtin_amdgcn_mfma_f32_16x16x32_bf16(al, bh, ca[i], 0, 0, 0);
                } else {
                    cb[i] = __builtin_amdgcn_mfma_f32_16x16x32_bf16(ar, bh, cb[i], 0, 0, 0);
                    cb[i] = __builtin_amdgcn_mfma_f32_16x16x32_bf16(ar, bl, cb[i], 0, 0, 0);
                    cb[i] = __builtin_amdgcn_mfma_f32_16x16x32_bf16(al, bh, cb[i], 0, 0, 0);
                }
            }
        }
        // (e) update: h' = z*h + (1-z)*cand; refresh fp32 + bf16 mirrors; write out
#pragma unroll
        for (int i = 0; i < 2; ++i) {
            int n = (w * 2 + i) * 16 + mc;
            int fi0 = ((((n >> 5) * 64) + (((n >> 3) & 3) * 16)) << 3) + (n & 7);
#pragma unroll
            for (int r = 0; r < 4; ++r) {
                int m = quad * 4 + r;
                bool valid = (t < Lr[r]);
                float cd = ftanh(ca[i][r] + cb[i][r] + gC[i][r]);
                float z = zs[m][n];
                float h = hs[m][n];
                float hn = z * h + (1.f - z) * cd;
                float ov = valid ? hn : 0.f;
                if (valid) {
                    hs[m][n] = hn;
                    unsigned short hi = f2bf(hn);
                    int fi = fi0 + (m << 3);
                    hfHu[fi] = hi;
                    hfLu[fi] = f2bf(hn - bf2f(hi));
                }
                outbuf[((size_t)(rg0 + m) * T + tir[r]) * 256 + dir * 128 + n] = ov;
            }
        }
        __syncthreads();
        // (f) rotate prefetch registers
        if (t + 1 < T) {
#pragma unroll
            for (int r = 0; r < 4; ++r) {
                tir[r] = tirn[r];
#pragma unroll
                for (int i = 0; i < 4; ++i) gG[i][r] = gGn[i][r];
#pragma unroll
                for (int i = 0; i < 2; ++i) gC[i][r] = gCn[i][r];
            }
        }
    }
}

// ---------------- fused attention: proj MFMA + score + softmax + weighted sum ----------------
__global__ __launch_bounds__(256) void attn_fused(
    const float* __restrict__ outv,   // [n*T, 256]
    const uint4* __restrict__ WaH, const uint4* __restrict__ WaL,  // [8 nt][8 kc][64]
    const float* __restrict__ ba, const float* __restrict__ u,
    float* __restrict__ att_out,      // rows (attRowOff+n)*T
    float* __restrict__ vec,          // [n, 256]
    int T, int attRowOff)
{
    __shared__ float lowS[50][260];
    __shared__ float scoreS[64];
    __shared__ float attS[64];
    int n = blockIdx.x;
    int tid = threadIdx.x;
    int lane = tid & 63, w = tid >> 6;
    int quad = lane >> 4, mc = lane & 15;

    const float4* src4 = (const float4*)(outv + (size_t)n * T * 256);
    for (int idx = tid; idx < T * 64; idx += 256) {
        int row = idx >> 6, c4 = idx & 63;
        float4 v = src4[idx];
        *(float4*)&lowS[row][c4 * 4] = v;
    }
    __syncthreads();

    f32x4 acc[8];
#pragma unroll
    for (int j = 0; j < 8; ++j) acc[j] = (f32x4){0.f, 0.f, 0.f, 0.f};
    int rowA = w * 16 + mc;
    bool rowValid = rowA < T;
#pragma unroll
    for (int kc = 0; kc < 8; ++kc) {
        float v[8];
        if (rowValid) {
            const float* p = &lowS[rowA][kc * 32 + quad * 8];
#pragma unroll
            for (int j = 0; j < 8; ++j) v[j] = p[j];
        } else {
#pragma unroll
            for (int j = 0; j < 8; ++j) v[j] = 0.f;
        }
        short8 ah, al;
        cvt8(v, ah, al);
#pragma unroll
        for (int nt = 0; nt < 8; ++nt) {
            size_t idx = (((size_t)nt * 8 + kc) << 6) + lane;
            short8 bh = __builtin_bit_cast(short8, WaH[idx]);
            short8 bl = __builtin_bit_cast(short8, WaL[idx]);
            acc[nt] = __builtin_amdgcn_mfma_f32_16x16x32_bf16(ah, bh, acc[nt], 0, 0, 0);
            acc[nt] = __builtin_amdgcn_mfma_f32_16x16x32_bf16(ah, bl, acc[nt], 0, 0, 0);
            acc[nt] = __builtin_amdgcn_mfma_f32_16x16x32_bf16(al, bh, acc[nt], 0, 0, 0);
        }
    }
    float sc[4] = {0.f, 0.f, 0.f, 0.f};
#pragma unroll
    for (int nt = 0; nt < 8; ++nt) {
        int col = nt * 16 + mc;
        float bb = ba[col], uu = u[col];
#pragma unroll
        for (int r = 0; r < 4; ++r)
            sc[r] += ftanh(acc[nt][r] + bb) * uu;
    }
#pragma unroll
    for (int off = 1; off < 16; off <<= 1) {
#pragma unroll
        for (int r = 0; r < 4; ++r) sc[r] += __shfl_xor(sc[r], off);
    }
    if (mc == 0) {
#pragma unroll
        for (int r = 0; r < 4; ++r) scoreS[w * 16 + quad * 4 + r] = sc[r];
    }
    __syncthreads();
    if (w == 0) {
        float s = (lane < T) ? scoreS[lane] : -3.402823466e38f;
        float m = s;
#pragma unroll
        for (int off = 1; off < 64; off <<= 1) m = fmaxf(m, __shfl_xor(m, off));
        float e = (lane < T) ? __expf(s - m) : 0.f;
        float sum = e;
#pragma unroll
        for (int off = 1; off < 64; off <<= 1) sum += __shfl_xor(sum, off);
        float att = e / sum;
        attS[lane] = att;
        if (lane < T) att_out[(size_t)(attRowOff + n) * T + lane] = att;
    }
    __syncthreads();
    float a = 0.f;
    for (int t = 0; t < T; ++t) a += attS[t] * lowS[t][tid];
    vec[(size_t)n * 256 + tid] = a;
}

// ---------------- head: logits, log-softmax, loss(+reg), predict, accuracy ----------------
__global__ __launch_bounds__(256) void head_kernel(
    const float* __restrict__ dvec, const float* __restrict__ wp, const float* __restrict__ bp,
    const int* __restrict__ y,
    const float* __restrict__ wa_l, const float* __restrict__ ba_l, const float* __restrict__ wa_h,
    const float* __restrict__ uw, const float* __restrict__ us,
    float* __restrict__ out)
{
    __shared__ float lg[64][10];
    __shared__ float red[256];
    int tid = threadIdx.x;
    for (int idx = tid; idx < 640; idx += 256) {
        int r = idx / 10, c = idx % 10;
        float a = bp[c];
        const float* dv = dvec + r * 256;
        for (int k = 0; k < 256; ++k) a += dv[k] * wp[k * 10 + c];
        lg[r][c] = a;
    }
    __syncthreads();
    float lossv = 0.f, corr = 0.f;
    if (tid < 64) {
        float m = lg[tid][0]; int arg = 0;
        for (int c = 1; c < 10; ++c) if (lg[tid][c] > m) { m = lg[tid][c]; arg = c; }
        float se = 0.f;
        for (int c = 0; c < 10; ++c) se += __expf(lg[tid][c] - m);
        float lse = m + __logf(se);
        int yy = y[tid];
        lossv = -(lg[tid][yy] - lse);
        corr = (yy == arg) ? 1.f : 0.f;
        out[1 + tid] = (float)arg;
    }
    float rs = 0.f;
    for (int i = tid; i < 32768; i += 256) {
        float v = wa_l[i]; rs += v * v;
        float w = wa_h[i]; rs += 2.f * w * w;
    }
    if (tid < 128) {
        float v1 = ba_l[tid], v2 = uw[tid], v3 = us[tid];
        rs += v1 * v1 + v2 * v2 + v3 * v3;
    }
    red[tid] = lossv; __syncthreads();
    for (int o = 128; o > 0; o >>= 1) { if (tid < o) red[tid] += red[tid + o]; __syncthreads(); }
    float totLoss = red[0]; __syncthreads();
    red[tid] = corr; __syncthreads();
    for (int o = 128; o > 0; o >>= 1) { if (tid < o) red[tid] += red[tid + o]; __syncthreads(); }
    float totCorr = red[0]; __syncthreads();
    red[tid] = rs; __syncthreads();
    for (int o = 128; o > 0; o >>= 1) { if (tid < o) red[tid] += red[tid + o]; __syncthreads(); }
    float totReg = red[0];
    if (tid == 0) {
        out[0] = totLoss / 64.f + 0.01f * totReg;
        out[65] = totCorr / 64.f;
    }
}

extern "C" void kernel_launch(void* const* d_in, const int* in_sizes, int n_in,
                              void* d_out, int out_size, void* d_ws, size_t ws_size,
                              hipStream_t stream)
{
    const float* X    = (const float*)d_in[0];
    const int*   y    = (const int*)d_in[1];
    const int*   slen = (const int*)d_in[2];
    const int*   dlen = (const int*)d_in[3];
    const float* wgf_l = (const float*)d_in[6];
    const float* bgf_l = (const float*)d_in[7];
    const float* wcf_l = (const float*)d_in[8];
    const float* bcf_l = (const float*)d_in[9];
    const float* wgb_l = (const float*)d_in[10];
    const float* bgb_l = (const float*)d_in[11];
    const float* wcb_l = (const float*)d_in[12];
    const float* bcb_l = (const float*)d_in[13];
    const float* wa_l  = (const float*)d_in[14];
    const float* ba_l  = (const float*)d_in[15];
    const float* wgf_h = (const float*)d_in[16];
    const float* bgf_h = (const float*)d_in[17];
    const float* wcf_h = (const float*)d_in[18];
    const float* bcf_h = (const float*)d_in[19];
    const float* wgb_h = (const float*)d_in[20];
    const float* bgb_h = (const float*)d_in[21];
    const float* wcb_h = (const float*)d_in[22];
    const float* bcb_h = (const float*)d_in[23];
    const float* wa_h  = (const float*)d_in[24];
    const float* ba_h  = (const float*)d_in[25];
    const float* uw    = (const float*)d_in[26];
    const float* us    = (const float*)d_in[27];
    const float* wp    = (const float*)d_in[28];
    const float* bp    = (const float*)d_in[29];
    float* out = (float*)d_out;

    int NCH = 1;
    while (NCH < 8) {
        size_t M1t = 128000ull / NCH;
        size_t needB = (M1t * 1248ull + 5400000ull) * 4ull;
        if (needB <= ws_size) break;
        NCH *= 2;
    }
    size_t nRows = 2560 / NCH;
    size_t M1 = nRows * 50;

    float* G1     = (float*)d_ws;            // M1*768
    float* low    = G1 + M1 * 768;           // M1*256
    float* AXf    = low + M1 * 256;          // M1*224
    float* sent   = AXf + M1 * 224;          // 655360
    float* Gs     = sent + 655360;           // 1966080
    float* high   = Gs + 1966080;            // 655360
    float* dvec   = high + 655360;           // 16384
    float* pSf    = dvec + 16384;            // 655360
    float* WpackL = pSf + 655360;            // 153600
    float* biasL  = WpackL + 153600;         // 768
    float* WLf    = biasL + 768;             // 172032
    float* WpackH = WLf + 172032;            // 196608
    float* biasH  = WpackH + 196608;         // 768
    float* WHf    = biasH + 768;             // 196608
    float* WaLf   = WHf + 196608;            // 32768
    float* WaHf   = WaLf + 32768;            // 32768
    float* RgLf   = WaHf + 32768;            // 65536
    float* RcLf   = RgLf + 65536;            // 32768
    float* RgHf   = RcLf + 32768;            // 65536
    float* RcHf   = RgHf + 65536;            // 32768

    uint4* AXh = (uint4*)AXf;           uint4* AXl = (uint4*)(AXf + M1 * 112);
    uint4* pSh = (uint4*)pSf;           uint4* pSl = (uint4*)(pSf + 327680);
    uint4* WLh = (uint4*)WLf;           uint4* WLl = (uint4*)(WLf + 86016);
    uint4* WHh = (uint4*)WHf;           uint4* WHl = (uint4*)(WHf + 98304);
    uint4* WaLh = (uint4*)WaLf;         uint4* WaLl = (uint4*)(WaLf + 16384);
    uint4* WaHh = (uint4*)WaHf;         uint4* WaHl = (uint4*)(WaHf + 16384);
    uint4* RgLH = (uint4*)RgLf;         uint4* RgLL = (uint4*)(RgLf + 32768);
    uint4* RcLH = (uint4*)RcLf;         uint4* RcLL = (uint4*)(RcLf + 16384);
    uint4* RgHH = (uint4*)RgHf;         uint4* RgHL = (uint4*)(RgHf + 32768);
    uint4* RcHH = (uint4*)RcHf;         uint4* RcHL = (uint4*)(RcHf + 16384);

    pack_weights<<<600, 256, 0, stream>>>(wgf_l, bgf_l, wcf_l, bcf_l, wgb_l, bgb_l, wcb_l, bcb_l,
                                          WpackL, biasL, 200);
    pack_weights<<<768, 256, 0, stream>>>(wgf_h, bgf_h, wcf_h, bcf_h, wgb_h, bgb_h, wcb_h, bcb_h,
                                          WpackH, biasH, 256);
    pack_w_frag<<<84, 256, 0, stream>>>(WpackL, WLh, WLl, 48, 7, 200, 768);
    pack_w_frag<<<96, 256, 0, stream>>>(WpackH, WHh, WHl, 48, 8, 256, 768);
    pack_w_frag<<<16, 256, 0, stream>>>(wa_l, WaLh, WaLl, 8, 8, 256, 128);
    pack_w_frag<<<16, 256, 0, stream>>>(wa_h, WaHh, WaHl, 8, 8, 256, 128);
    pack_rec<<<dim3(16, 4), 256, 0, stream>>>(wgf_l + 200 * 256, wgb_l + 200 * 256,
                                              wcf_l + 200 * 128, wcb_l + 200 * 128,
                                              RgLH, RgLL, RcLH, RcLL);
    pack_rec<<<dim3(16, 4), 256, 0, stream>>>(wgf_h + 256 * 256, wgb_h + 256 * 256,
                                              wcf_h + 256 * 128, wcb_h + 256 * 128,
                                              RgHH, RgHL, RcHH, RcHL);

    for (int c = 0; c < NCH; ++c) {
        const float* Xc = X + (size_t)c * nRows * 50 * 200;
        int Mr16 = (int)(M1 / 16);
        pack_a_frag<<<(Mr16 * 7 * 64 + 255) / 256, 256, 0, stream>>>(Xc, AXh, AXl, Mr16, 7, 200);
        mfma_gemm<<<dim3((int)(M1 / 128), 6), 256, 0, stream>>>(AXh, AXl, WLh, WLl, biasL, G1, 7, 768, 0);
        bigru_mfma<<<(int)(nRows / 16) * 2, 256, 0, stream>>>(G1, RgLH, RgLL, RcLH, RcLL,
                                                              slen, low, (int)(c * nRows), 50);
        attn_fused<<<(int)nRows, 256, 0, stream>>>(low, WaLh, WaLl, ba_l, uw,
                                                   out + 66, sent + (size_t)c * nRows * 256, 50, (int)(c * nRows));
    }
    // ---- sentence level ----
    pack_a_frag<<<(160 * 8 * 64 + 255) / 256, 256, 0, stream>>>(sent, pSh, pSl, 160, 8, 256);
    mfma_gemm<<<dim3(20, 6), 256, 0, stream>>>(pSh, pSl, WHh, WHl, biasH, Gs, 8, 768, 0);
    bigru_mfma<<<8, 256, 0, stream>>>(Gs, RgHH, RgHL, RcHH, RcHL, dlen, high, 0, 40);
    attn_fused<<<64, 256, 0, stream>>>(high, WaHh, WaHl, ba_h, us, out + 128066, dvec, 40, 0);
    head_kernel<<<1, 256, 0, stream>>>(dvec, wp, bp, y, wa_l, ba_l, wa_h, uw, us, out);
}

// Round 10
// 1228.153 us; speedup vs baseline: 3.3195x; 1.0391x over previous
//
#include <hip/hip_runtime.h>
#include <hip/hip_bf16.h>

// HAN_81801947119983 — round 10: R9 with the prep_all bias-index bug fixed.
// R9 bug: `c = idx & 767` (767 has bit8 clear) left bias[256..511] unwritten ->
// bw gate biases (TF init 1.0) were poison -> predict wrong. Explicit branch now.
// Structure: R5-exact bigru_mfma + one fused prep kernel (10 launches total).
// B=64, D=40, S=50, E=200, H=128, C=10. N1=2560 word rows (T=50), 64 doc rows (T=40).
// G cols: [0:256) fw gates, [256:384) fw cand, [384:640) bw gates, [640:768) bw cand.
// MFMA 16x16x32 bf16: A frag lane holds A[m=lane&15][k=quad*8+j]; B frag B[k][n=lane&15];
// C/D col=lane&15, row=quad*4+reg.  Pack uint4 idx: ((tile*KC+kc)*4+quad)*16+(lane&15).

typedef __attribute__((ext_vector_type(8))) short short8;
typedef __attribute__((ext_vector_type(4))) float f32x4;

__device__ __forceinline__ float fsigmoid(float x) { return 1.f / (1.f + __expf(-x)); }
__device__ __forceinline__ float ftanh(float x)    { float e = __expf(2.f * x); return 1.f - 2.f / (e + 1.f); }

__device__ __forceinline__ unsigned short f2bf(float x) {
    unsigned int u = __builtin_bit_cast(unsigned int, x);
    u += 0x7fffu + ((u >> 16) & 1u);
    return (unsigned short)(u >> 16);
}
__device__ __forceinline__ float bf2f(unsigned short h) {
    unsigned int u = ((unsigned int)h) << 16;
    return __builtin_bit_cast(float, u);
}
__device__ __forceinline__ uint4 pack8(const unsigned short* v) {
    uint4 r;
    r.x = (unsigned int)v[0] | ((unsigned int)v[1] << 16);
    r.y = (unsigned int)v[2] | ((unsigned int)v[3] << 16);
    r.z = (unsigned int)v[4] | ((unsigned int)v[5] << 16);
    r.w = (unsigned int)v[6] | ((unsigned int)v[7] << 16);
    return r;
}
__device__ __forceinline__ void cvt8(const float* v, short8& hi, short8& lo) {
    unsigned short h[8], l[8];
#pragma unroll
    for (int j = 0; j < 8; ++j) {
        unsigned short hh = f2bf(v[j]);
        h[j] = hh;
        l[j] = f2bf(v[j] - bf2f(hh));
    }
    uint4 uh = pack8(h), ul = pack8(l);
    hi = __builtin_bit_cast(short8, uh);
    lo = __builtin_bit_cast(short8, ul);
}

// ---------------- pack A (row-major [Mr x Ks] fp32) into frag-order hi/lo bf16 ----------------
__global__ __launch_bounds__(256) void pack_a_frag(
    const float* __restrict__ src, uint4* __restrict__ dstH, uint4* __restrict__ dstL,
    int Mr16, int KC, int Ks)
{
    int idx = blockIdx.x * 256 + threadIdx.x;
    if (idx >= Mr16 * KC * 64) return;
    int lane = idx & 63;
    int g = idx >> 6;
    int mb = g / KC, kc = g - mb * KC;
    int m = lane & 15, quad = lane >> 4;
    int row = mb * 16 + m;
    int k0 = kc * 32 + quad * 8;
    const float* s = src + (size_t)row * Ks;
    unsigned short hi[8], lo[8];
#pragma unroll
    for (int j = 0; j < 8; ++j) {
        float x = (k0 + j < Ks) ? s[k0 + j] : 0.f;
        unsigned short h = f2bf(x);
        hi[j] = h;
        lo[j] = f2bf(x - bf2f(h));
    }
    dstH[idx] = pack8(hi);
    dstL[idx] = pack8(lo);
}

// ---------------- prep_all helpers ----------------
__device__ __forceinline__ void packw4(
    int idx, int KC, int Ks,
    const float* __restrict__ s0, const float* __restrict__ s1,
    const float* __restrict__ s2, const float* __restrict__ s3,
    uint4* __restrict__ dH, uint4* __restrict__ dL)
{
    // concat cols: [0:256)=s0 (w256), [256:384)=s1 (w128), [384:640)=s2 (w256), [640:768)=s3 (w128)
    int lane = idx & 63;
    int g = idx >> 6;
    int nb = g / KC, kc = g - nb * KC;
    int m = lane & 15, quad = lane >> 4;
    int n = nb * 16 + m;
    int k0 = kc * 32 + quad * 8;
    unsigned short hi[8], lo[8];
#pragma unroll
    for (int j = 0; j < 8; ++j) {
        int k = k0 + j;
        float x = 0.f;
        if (k < Ks) {
            if (n < 256)      x = s0[(size_t)k * 256 + n];
            else if (n < 384) x = s1[(size_t)k * 128 + (n - 256)];
            else if (n < 640) x = s2[(size_t)k * 256 + (n - 384)];
            else              x = s3[(size_t)k * 128 + (n - 640)];
        }
        unsigned short h = f2bf(x);
        hi[j] = h;
        lo[j] = f2bf(x - bf2f(h));
    }
    dH[idx] = pack8(hi);
    dL[idx] = pack8(lo);
}

__device__ __forceinline__ void packw1(
    int idx, int KC, int Ks, const float* __restrict__ src, int N,
    uint4* __restrict__ dH, uint4* __restrict__ dL)
{
    int lane = idx & 63;
    int g = idx >> 6;
    int nb = g / KC, kc = g - nb * KC;
    int m = lane & 15, quad = lane >> 4;
    int n = nb * 16 + m;
    int k0 = kc * 32 + quad * 8;
    unsigned short hi[8], lo[8];
#pragma unroll
    for (int j = 0; j < 8; ++j) {
        int k = k0 + j;
        float x = (k < Ks) ? src[(size_t)k * N + n] : 0.f;
        unsigned short h = f2bf(x);
        hi[j] = h;
        lo[j] = f2bf(x - bf2f(h));
    }
    dH[idx] = pack8(hi);
    dL[idx] = pack8(lo);
}

// ---------------- ONE prep kernel: all weight frag-packs + biases ----------------
// segments (flat idx): WL 21504 | WH 24576 | WaL 4096 | WaH 4096 |
//                      RgL 8192 | RcL 4096 | RgH 8192 | RcH 4096 | bias 1536  (=80384)
__global__ __launch_bounds__(256) void prep_all(
    const float* __restrict__ wgf_l, const float* __restrict__ bgf_l,
    const float* __restrict__ wcf_l, const float* __restrict__ bcf_l,
    const float* __restrict__ wgb_l, const float* __restrict__ bgb_l,
    const float* __restrict__ wcb_l, const float* __restrict__ bcb_l,
    const float* __restrict__ wgf_h, const float* __restrict__ bgf_h,
    const float* __restrict__ wcf_h, const float* __restrict__ bcf_h,
    const float* __restrict__ wgb_h, const float* __restrict__ bgb_h,
    const float* __restrict__ wcb_h, const float* __restrict__ bcb_h,
    const float* __restrict__ wa_l, const float* __restrict__ wa_h,
    uint4* __restrict__ WLh, uint4* __restrict__ WLl,
    uint4* __restrict__ WHh, uint4* __restrict__ WHl,
    uint4* __restrict__ WaLh, uint4* __restrict__ WaLl,
    uint4* __restrict__ WaHh, uint4* __restrict__ WaHl,
    uint4* __restrict__ RgLH, uint4* __restrict__ RgLL,
    uint4* __restrict__ RcLH, uint4* __restrict__ RcLL,
    uint4* __restrict__ RgHH, uint4* __restrict__ RgHL,
    uint4* __restrict__ RcHH, uint4* __restrict__ RcHL,
    float* __restrict__ biasL, float* __restrict__ biasH)
{
    int idx = blockIdx.x * 256 + threadIdx.x;
    if (idx < 21504) {                                   // WL: 48 nt x 7 kc, Ks=200
        packw4(idx, 7, 200, wgf_l, wcf_l, wgb_l, wcb_l, WLh, WLl);
        return;
    }
    idx -= 21504;
    if (idx < 24576) {                                   // WH: 48 nt x 8 kc, Ks=256
        packw4(idx, 8, 256, wgf_h, wcf_h, wgb_h, wcb_h, WHh, WHl);
        return;
    }
    idx -= 24576;
    if (idx < 4096) { packw1(idx, 8, 256, wa_l, 128, WaLh, WaLl); return; }
    idx -= 4096;
    if (idx < 4096) { packw1(idx, 8, 256, wa_h, 128, WaHh, WaHl); return; }
    idx -= 4096;
    if (idx < 8192) {                                    // RgL: fw | bw halves
        int sel = idx >> 12, li = idx & 4095;
        packw1(li, 4, 128, (sel ? wgb_l : wgf_l) + 200 * 256, 256,
               RgLH + sel * 4096, RgLL + sel * 4096);
        return;
    }
    idx -= 8192;
    if (idx < 4096) {                                    // RcL
        int sel = idx >> 11, li = idx & 2047;
        packw1(li, 4, 128, (sel ? wcb_l : wcf_l) + 200 * 128, 128,
               RcLH + sel * 2048, RcLL + sel * 2048);
        return;
    }
    idx -= 4096;
    if (idx < 8192) {                                    // RgH
        int sel = idx >> 12, li = idx & 4095;
        packw1(li, 4, 128, (sel ? wgb_h : wgf_h) + 256 * 256, 256,
               RgHH + sel * 4096, RgHL + sel * 4096);
        return;
    }
    idx -= 8192;
    if (idx < 4096) {                                    // RcH
        int sel = idx >> 11, li = idx & 2047;
        packw1(li, 4, 128, (sel ? wcb_h : wcf_h) + 256 * 128, 128,
               RcHH + sel * 2048, RcHL + sel * 2048);
        return;
    }
    idx -= 4096;
    if (idx < 1536) {                                    // biases (concat order) — FIXED indexing
        if (idx < 768) {
            int c = idx;
            float v;
            if (c < 256) v = bgf_l[c];
            else if (c < 384) v = bcf_l[c - 256];
            else if (c < 640) v = bgb_l[c - 384];
            else v = bcb_l[c - 640];
            biasL[c] = v;
        } else {
            int c = idx - 768;
            float v;
            if (c < 256) v = bgf_h[c];
            else if (c < 384) v = bcf_h[c - 256];
            else if (c < 640) v = bgb_h[c - 384];
            else v = bcb_h[c - 640];
            biasH[c] = v;
        }
    }
}

// ---------------- MFMA GEMM: C = A @ W + bias, split-bf16 3-product ----------------
__global__ __launch_bounds__(256) void mfma_gemm(
    const uint4* __restrict__ Ah, const uint4* __restrict__ Al,
    const uint4* __restrict__ Bh, const uint4* __restrict__ Bl,
    const float* __restrict__ bias, float* __restrict__ C,
    int KC, int ldc, int act)
{
    int tid = threadIdx.x;
    int lane = tid & 63;
    int w = tid >> 6;
    int wm = w >> 1, wn = w & 1;
    int quad = lane >> 4, m = lane & 15;
    int bm = blockIdx.x, bn = blockIdx.y;
    f32x4 acc[4][4];
#pragma unroll
    for (int i = 0; i < 4; ++i)
#pragma unroll
        for (int j = 0; j < 4; ++j) acc[i][j] = (f32x4){0.f, 0.f, 0.f, 0.f};

    size_t aBase[4], bBase[4];
#pragma unroll
    for (int i = 0; i < 4; ++i) {
        aBase[i] = ((size_t)(bm * 8 + wm * 4 + i) * KC) * 64 + quad * 16 + m;
        bBase[i] = ((size_t)(bn * 8 + wn * 4 + i) * KC) * 64 + quad * 16 + m;
    }
    for (int kc = 0; kc < KC; ++kc) {
        short8 ah[4], al[4], bh[4], bl[4];
#pragma unroll
        for (int i = 0; i < 4; ++i) {
            ah[i] = __builtin_bit_cast(short8, Ah[aBase[i]]);
            al[i] = __builtin_bit_cast(short8, Al[aBase[i]]);
            bh[i] = __builtin_bit_cast(short8, Bh[bBase[i]]);
            bl[i] = __builtin_bit_cast(short8, Bl[bBase[i]]);
            aBase[i] += 64; bBase[i] += 64;
        }
#pragma unroll
        for (int i = 0; i < 4; ++i)
#pragma unroll
            for (int j = 0; j < 4; ++j) {
                acc[i][j] = __builtin_amdgcn_mfma_f32_16x16x32_bf16(ah[i], bh[j], acc[i][j], 0, 0, 0);
                acc[i][j] = __builtin_amdgcn_mfma_f32_16x16x32_bf16(ah[i], bl[j], acc[i][j], 0, 0, 0);
                acc[i][j] = __builtin_amdgcn_mfma_f32_16x16x32_bf16(al[i], bh[j], acc[i][j], 0, 0, 0);
            }
    }
#pragma unroll
    for (int i = 0; i < 4; ++i) {
        int row0 = bm * 128 + wm * 64 + i * 16 + quad * 4;
#pragma unroll
        for (int j = 0; j < 4; ++j) {
            int col = bn * 128 + wn * 64 + j * 16 + m;
            float b = bias[col];
#pragma unroll
            for (int r = 0; r < 4; ++r) {
                float v = acc[i][j][r] + b;
                if (act) v = ftanh(v);
                C[(size_t)(row0 + r) * ldc + col] = v;
            }
        }
    }
}

// ---------------- MFMA BiGRU (R5 exact): 16 rows x 1 dir per block, 4 waves ----------------
__global__ __launch_bounds__(256) void bigru_mfma(
    const float* __restrict__ G,      // [nRows*T, 768] chunk-local
    const uint4* __restrict__ WgH, const uint4* __restrict__ WgL,  // [2 dirs][16 nt][4 kc][64]
    const uint4* __restrict__ WcH, const uint4* __restrict__ WcL,  // [2 dirs][8 nt][4 kc][64]
    const int* __restrict__ lens,
    float* __restrict__ outbuf,       // [nRows*T, 256] chunk-local (zeros at invalid)
    int rowOff, int T)
{
    __shared__ float hs[16][132];
    __shared__ float zs[16][132];
    __shared__ uint4 hfH[4][64], hfL[4][64];
    __shared__ uint4 rfH[4][64], rfL[4][64];
    __shared__ int Ls[16];

    int tid = threadIdx.x;
    int dir = blockIdx.x & 1;
    int rg0 = (blockIdx.x >> 1) * 16;
    int lane = tid & 63, w = tid >> 6;
    int quad = lane >> 4, mc = lane & 15;
    for (int i = tid; i < 16 * 132; i += 256) { (&hs[0][0])[i] = 0.f; }
    for (int i = tid; i < 256; i += 256) { hfH[0][i] = (uint4){0,0,0,0}; hfL[0][i] = (uint4){0,0,0,0}; }
    if (tid < 16) Ls[tid] = lens[rowOff + rg0 + tid];
    __syncthreads();
    const int goff = dir * 384;
    unsigned short* hfHu = (unsigned short*)hfH;
    unsigned short* hfLu = (unsigned short*)hfL;
    unsigned short* rfHu = (unsigned short*)rfH;
    unsigned short* rfLu = (unsigned short*)rfL;

    for (int t = 0; t < T; ++t) {
        int Lr[4], tir[4];
#pragma unroll
        for (int r = 0; r < 4; ++r) {
            int L = Ls[quad * 4 + r];
            Lr[r] = L;
            tir[r] = dir ? ((t < L) ? (L - 1 - t) : t) : t;
        }
        // prefetch G (consumed after MFMAs)
        float gG[4][4], gC[2][4];
#pragma unroll
        for (int r = 0; r < 4; ++r) {
            const float* gbase = &G[((size_t)(rg0 + quad * 4 + r) * T + tir[r]) * 768 + goff];
#pragma unroll
            for (int i = 0; i < 4; ++i) gG[i][r] = gbase[(w * 4 + i) * 16 + mc];
#pragma unroll
            for (int i = 0; i < 2; ++i) gC[i][r] = gbase[256 + (w * 2 + i) * 16 + mc];
        }
        // gates MFMA: wave handles n-tiles w*4..w*4+3 of 16
        f32x4 ga[4];
#pragma unroll
        for (int i = 0; i < 4; ++i) ga[i] = (f32x4){0.f, 0.f, 0.f, 0.f};
#pragma unroll
        for (int kc = 0; kc < 4; ++kc) {
            short8 ah = __builtin_bit_cast(short8, hfH[kc][lane]);
            short8 al = __builtin_bit_cast(short8, hfL[kc][lane]);
#pragma unroll
            for (int i = 0; i < 4; ++i) {
                size_t idx = (((size_t)(dir * 16 + w * 4 + i) * 4 + kc) << 6) + lane;
                short8 bh = __builtin_bit_cast(short8, WgH[idx]);
                short8 bl = __builtin_bit_cast(short8, WgL[idx]);
                ga[i] = __builtin_amdgcn_mfma_f32_16x16x32_bf16(ah, bh, ga[i], 0, 0, 0);
                ga[i] = __builtin_amdgcn_mfma_f32_16x16x32_bf16(ah, bl, ga[i], 0, 0, 0);
                ga[i] = __builtin_amdgcn_mfma_f32_16x16x32_bf16(al, bh, ga[i], 0, 0, 0);
            }
        }
        // gate elementwise: rh -> rf frags (u16), z -> zs
#pragma unroll
        for (int i = 0; i < 4; ++i) {
            int n = (w * 4 + i) * 16 + mc;
#pragma unroll
            for (int r = 0; r < 4; ++r) {
                int m = quad * 4 + r;
                float s = fsigmoid(ga[i][r] + gG[i][r]);
                if (n < 128) {
                    float rh = s * hs[m][n];
                    unsigned short hi = f2bf(rh);
                    int fi = ((((n >> 5) * 64) + (((n >> 3) & 3) * 16) + m) << 3) + (n & 7);
                    rfHu[fi] = hi;
                    rfLu[fi] = f2bf(rh - bf2f(hi));
                } else {
                    zs[m][n - 128] = s;
                }
            }
        }
        __syncthreads();
        // cand MFMA: wave handles n-tiles w*2..w*2+1 of 8
        f32x4 ca[2];
#pragma unroll
        for (int i = 0; i < 2; ++i) ca[i] = (f32x4){0.f, 0.f, 0.f, 0.f};
#pragma unroll
        for (int kc = 0; kc < 4; ++kc) {
            short8 ar = __builtin_bit_cast(short8, rfH[kc][lane]);
            short8 al = __builtin_bit_cast(short8, rfL[kc][lane]);
#pragma unroll
            for (int i = 0; i < 2; ++i) {
                size_t idx = (((size_t)(dir * 8 + w * 2 + i) * 4 + kc) << 6) + lane;
                short8 bh = __builtin_bit_cast(short8, WcH[idx]);
                short8 bl = __builtin_bit_cast(short8, WcL[idx]);
                ca[i] = __builtin_amdgcn_mfma_f32_16x16x32_bf16(ar, bh, ca[i], 0, 0, 0);
                ca[i] = __builtin_amdgcn_mfma_f32_16x16x32_bf16(ar, bl, ca[i], 0, 0, 0);
                ca[i] = __builtin_amdgcn_mfma_f32_16x16x32_bf16(al, bh, ca[i], 0, 0, 0);
            }
        }
        // update: h' = z*h + (1-z)*cand; refresh fp32 + bf16 mirrors; write out
#pragma unroll
        for (int i = 0; i < 2; ++i) {
            int n = (w * 2 + i) * 16 + mc;
            int fi0 = ((((n >> 5) * 64) + (((n >> 3) & 3) * 16)) << 3) + (n & 7);
#pragma unroll
            for (int r = 0; r < 4; ++r) {
                int m = quad * 4 + r;
                bool valid = (t < Lr[r]);
                float cd = ftanh(ca[i][r] + gC[i][r]);
                float z = zs[m][n];
                float h = hs[m][n];
                float hn = z * h + (1.f - z) * cd;
                float ov = valid ? hn : 0.f;
                if (valid) {
                    hs[m][n] = hn;
                    unsigned short hi = f2bf(hn);
                    int fi = fi0 + (m << 3);
                    hfHu[fi] = hi;
                    hfLu[fi] = f2bf(hn - bf2f(hi));
                }
                outbuf[((size_t)(rg0 + m) * T + tir[r]) * 256 + dir * 128 + n] = ov;
            }
        }
        __syncthreads();
    }
}

// ---------------- fused attention: proj MFMA + score + softmax + weighted sum ----------------
__global__ __launch_bounds__(256) void attn_fused(
    const float* __restrict__ outv,   // [n*T, 256]
    const uint4* __restrict__ WaH, const uint4* __restrict__ WaL,  // [8 nt][8 kc][64]
    const float* __restrict__ ba, const float* __restrict__ u,
    float* __restrict__ att_out,      // rows (attRowOff+n)*T
    float* __restrict__ vec,          // [n, 256]
    int T, int attRowOff)
{
    __shared__ float lowS[50][260];
    __shared__ float scoreS[64];
    __shared__ float attS[64];
    int n = blockIdx.x;
    int tid = threadIdx.x;
    int lane = tid & 63, w = tid >> 6;
    int quad = lane >> 4, mc = lane & 15;

    const float4* src4 = (const float4*)(outv + (size_t)n * T * 256);
    for (int idx = tid; idx < T * 64; idx += 256) {
        int row = idx >> 6, c4 = idx & 63;
        float4 v = src4[idx];
        *(float4*)&lowS[row][c4 * 4] = v;
    }
    __syncthreads();

    f32x4 acc[8];
#pragma unroll
    for (int j = 0; j < 8; ++j) acc[j] = (f32x4){0.f, 0.f, 0.f, 0.f};
    int rowA = w * 16 + mc;
    bool rowValid = rowA < T;
#pragma unroll
    for (int kc = 0; kc < 8; ++kc) {
        float v[8];
        if (rowValid) {
            const float* p = &lowS[rowA][kc * 32 + quad * 8];
#pragma unroll
            for (int j = 0; j < 8; ++j) v[j] = p[j];
        } else {
#pragma unroll
            for (int j = 0; j < 8; ++j) v[j] = 0.f;
        }
        short8 ah, al;
        cvt8(v, ah, al);
#pragma unroll
        for (int nt = 0; nt < 8; ++nt) {
            size_t idx = (((size_t)nt * 8 + kc) << 6) + lane;
            short8 bh = __builtin_bit_cast(short8, WaH[idx]);
            short8 bl = __builtin_bit_cast(short8, WaL[idx]);
            acc[nt] = __builtin_amdgcn_mfma_f32_16x16x32_bf16(ah, bh, acc[nt], 0, 0, 0);
            acc[nt] = __builtin_amdgcn_mfma_f32_16x16x32_bf16(ah, bl, acc[nt], 0, 0, 0);
            acc[nt] = __builtin_amdgcn_mfma_f32_16x16x32_bf16(al, bh, acc[nt], 0, 0, 0);
        }
    }
    float sc[4] = {0.f, 0.f, 0.f, 0.f};
#pragma unroll
    for (int nt = 0; nt < 8; ++nt) {
        int col = nt * 16 + mc;
        float bb = ba[col], uu = u[col];
#pragma unroll
        for (int r = 0; r < 4; ++r)
            sc[r] += ftanh(acc[nt][r] + bb) * uu;
    }
#pragma unroll
    for (int off = 1; off < 16; off <<= 1) {
#pragma unroll
        for (int r = 0; r < 4; ++r) sc[r] += __shfl_xor(sc[r], off);
    }
    if (mc == 0) {
#pragma unroll
        for (int r = 0; r < 4; ++r) scoreS[w * 16 + quad * 4 + r] = sc[r];
    }
    __syncthreads();
    if (w == 0) {
        float s = (lane < T) ? scoreS[lane] : -3.402823466e38f;
        float m = s;
#pragma unroll
        for (int off = 1; off < 64; off <<= 1) m = fmaxf(m, __shfl_xor(m, off));
        float e = (lane < T) ? __expf(s - m) : 0.f;
        float sum = e;
#pragma unroll
        for (int off = 1; off < 64; off <<= 1) sum += __shfl_xor(sum, off);
        float att = e / sum;
        attS[lane] = att;
        if (lane < T) att_out[(size_t)(attRowOff + n) * T + lane] = att;
    }
    __syncthreads();
    float a = 0.f;
    for (int t = 0; t < T; ++t) a += attS[t] * lowS[t][tid];
    vec[(size_t)n * 256 + tid] = a;
}

// ---------------- head: logits, log-softmax, loss(+reg), predict, accuracy ----------------
__global__ __launch_bounds__(256) void head_kernel(
    const float* __restrict__ dvec, const float* __restrict__ wp, const float* __restrict__ bp,
    const int* __restrict__ y,
    const float* __restrict__ wa_l, const float* __restrict__ ba_l, const float* __restrict__ wa_h,
    const float* __restrict__ uw, const float* __restrict__ us,
    float* __restrict__ out)
{
    __shared__ float lg[64][10];
    __shared__ float red[256];
    int tid = threadIdx.x;
    for (int idx = tid; idx < 640; idx += 256) {
        int r = idx / 10, c = idx % 10;
        float a = bp[c];
        const float* dv = dvec + r * 256;
        for (int k = 0; k < 256; ++k) a += dv[k] * wp[k * 10 + c];
        lg[r][c] = a;
    }
    __syncthreads();
    float lossv = 0.f, corr = 0.f;
    if (tid < 64) {
        float m = lg[tid][0]; int arg = 0;
        for (int c = 1; c < 10; ++c) if (lg[tid][c] > m) { m = lg[tid][c]; arg = c; }
        float se = 0.f;
        for (int c = 0; c < 10; ++c) se += __expf(lg[tid][c] - m);
        float lse = m + __logf(se);
        int yy = y[tid];
        lossv = -(lg[tid][yy] - lse);
        corr = (yy == arg) ? 1.f : 0.f;
        out[1 + tid] = (float)arg;
    }
    float rs = 0.f;
    for (int i = tid; i < 32768; i += 256) {
        float v = wa_l[i]; rs += v * v;
        float w = wa_h[i]; rs += 2.f * w * w;
    }
    if (tid < 128) {
        float v1 = ba_l[tid], v2 = uw[tid], v3 = us[tid];
        rs += v1 * v1 + v2 * v2 + v3 * v3;
    }
    red[tid] = lossv; __syncthreads();
    for (int o = 128; o > 0; o >>= 1) { if (tid < o) red[tid] += red[tid + o]; __syncthreads(); }
    float totLoss = red[0]; __syncthreads();
    red[tid] = corr; __syncthreads();
    for (int o = 128; o > 0; o >>= 1) { if (tid < o) red[tid] += red[tid + o]; __syncthreads(); }
    float totCorr = red[0]; __syncthreads();
    red[tid] = rs; __syncthreads();
    for (int o = 128; o > 0; o >>= 1) { if (tid < o) red[tid] += red[tid + o]; __syncthreads(); }
    float totReg = red[0];
    if (tid == 0) {
        out[0] = totLoss / 64.f + 0.01f * totReg;
        out[65] = totCorr / 64.f;
    }
}

extern "C" void kernel_launch(void* const* d_in, const int* in_sizes, int n_in,
                              void* d_out, int out_size, void* d_ws, size_t ws_size,
                              hipStream_t stream)
{
    const float* X    = (const float*)d_in[0];
    const int*   y    = (const int*)d_in[1];
    const int*   slen = (const int*)d_in[2];
    const int*   dlen = (const int*)d_in[3];
    const float* wgf_l = (const float*)d_in[6];
    const float* bgf_l = (const float*)d_in[7];
    const float* wcf_l = (const float*)d_in[8];
    const float* bcf_l = (const float*)d_in[9];
    const float* wgb_l = (const float*)d_in[10];
    const float* bgb_l = (const float*)d_in[11];
    const float* wcb_l = (const float*)d_in[12];
    const float* bcb_l = (const float*)d_in[13];
    const float* wa_l  = (const float*)d_in[14];
    const float* ba_l  = (const float*)d_in[15];
    const float* wgf_h = (const float*)d_in[16];
    const float* bgf_h = (const float*)d_in[17];
    const float* wcf_h = (const float*)d_in[18];
    const float* bcf_h = (const float*)d_in[19];
    const float* wgb_h = (const float*)d_in[20];
    const float* bgb_h = (const float*)d_in[21];
    const float* wcb_h = (const float*)d_in[22];
    const float* bcb_h = (const float*)d_in[23];
    const float* wa_h  = (const float*)d_in[24];
    const float* ba_h  = (const float*)d_in[25];
    const float* uw    = (const float*)d_in[26];
    const float* us    = (const float*)d_in[27];
    const float* wp    = (const float*)d_in[28];
    const float* bp    = (const float*)d_in[29];
    float* out = (float*)d_out;

    int NCH = 1;
    while (NCH < 8) {
        size_t M1t = 128000ull / NCH;
        size_t needB = (M1t * 1248ull + 5400000ull) * 4ull;
        if (needB <= ws_size) break;
        NCH *= 2;
    }
    size_t nRows = 2560 / NCH;
    size_t M1 = nRows * 50;

    float* G1     = (float*)d_ws;            // M1*768
    float* low    = G1 + M1 * 768;           // M1*256
    float* AXf    = low + M1 * 256;          // M1*224
    float* sent   = AXf + M1 * 224;          // 655360
    float* Gs     = sent + 655360;           // 1966080
    float* high   = Gs + 1966080;            // 655360
    float* dvec   = high + 655360;           // 16384
    float* pSf    = dvec + 16384;            // 655360
    float* biasL  = pSf + 655360;            // 768
    float* biasH  = biasL + 768;             // 768
    float* WLf    = biasH + 768;             // 172032
    float* WHf    = WLf + 172032;            // 196608
    float* WaLf   = WHf + 196608;            // 32768
    float* WaHf   = WaLf + 32768;            // 32768
    float* RgLf   = WaHf + 32768;            // 65536
    float* RcLf   = RgLf + 65536;            // 32768
    float* RgHf   = RcLf + 32768;            // 65536
    float* RcHf   = RgHf + 65536;            // 32768

    uint4* AXh = (uint4*)AXf;           uint4* AXl = (uint4*)(AXf + M1 * 112);
    uint4* pSh = (uint4*)pSf;           uint4* pSl = (uint4*)(pSf + 327680);
    uint4* WLh = (uint4*)WLf;           uint4* WLl = (uint4*)(WLf + 86016);
    uint4* WHh = (uint4*)WHf;           uint4* WHl = (uint4*)(WHf + 98304);
    uint4* WaLh = (uint4*)WaLf;         uint4* WaLl = (uint4*)(WaLf + 16384);
    uint4* WaHh = (uint4*)WaHf;         uint4* WaHl = (uint4*)(WaHf + 16384);
    uint4* RgLH = (uint4*)RgLf;         uint4* RgLL = (uint4*)(RgLf + 32768);
    uint4* RcLH = (uint4*)RcLf;         uint4* RcLL = (uint4*)(RcLf + 16384);
    uint4* RgHH = (uint4*)RgHf;         uint4* RgHL = (uint4*)(RgHf + 32768);
    uint4* RcHH = (uint4*)RcHf;         uint4* RcHL = (uint4*)(RcHf + 16384);

    // ONE prep launch: all frag packs + biases (80384 work items)
    prep_all<<<(80384 + 255) / 256, 256, 0, stream>>>(
        wgf_l, bgf_l, wcf_l, bcf_l, wgb_l, bgb_l, wcb_l, bcb_l,
        wgf_h, bgf_h, wcf_h, bcf_h, wgb_h, bgb_h, wcb_h, bcb_h,
        wa_l, wa_h,
        WLh, WLl, WHh, WHl, WaLh, WaLl, WaHh, WaHl,
        RgLH, RgLL, RcLH, RcLL, RgHH, RgHL, RcHH, RcHL,
        biasL, biasH);

    for (int c = 0; c < NCH; ++c) {
        const float* Xc = X + (size_t)c * nRows * 50 * 200;
        int Mr16 = (int)(M1 / 16);
        pack_a_frag<<<(Mr16 * 7 * 64 + 255) / 256, 256, 0, stream>>>(Xc, AXh, AXl, Mr16, 7, 200);
        mfma_gemm<<<dim3((int)(M1 / 128), 6), 256, 0, stream>>>(AXh, AXl, WLh, WLl, biasL, G1, 7, 768, 0);
        bigru_mfma<<<(int)(nRows / 16) * 2, 256, 0, stream>>>(G1, RgLH, RgLL, RcLH, RcLL,
                                                              slen, low, (int)(c * nRows), 50);
        attn_fused<<<(int)nRows, 256, 0, stream>>>(low, WaLh, WaLl, ba_l, uw,
                                                   out + 66, sent + (size_t)c * nRows * 256, 50, (int)(c * nRows));
    }
    // ---- sentence level ----
    pack_a_frag<<<(160 * 8 * 64 + 255) / 256, 256, 0, stream>>>(sent, pSh, pSl, 160, 8, 256);
    mfma_gemm<<<dim3(20, 6), 256, 0, stream>>>(pSh, pSl, WHh, WHl, biasH, Gs, 8, 768, 0);
    bigru_mfma<<<8, 256, 0, stream>>>(Gs, RgHH, RgHL, RcHH, RcHL, dlen, high, 0, 40);
    attn_fused<<<64, 256, 0, stream>>>(high, WaHh, WaHl, ba_h, us, out + 128066, dvec, 40, 0);
    head_kernel<<<1, 256, 0, stream>>>(dvec, wp, bp, y, wa_l, ba_l, wa_h, uw, us, out);
}